// Round 2
// baseline (536.463 us; speedup 1.0000x reference)
//
#include <hip/hip_runtime.h>
#include <math.h>

#define T_TOK 16384
#define DDIM 2048
#define NEXP 256
#define TOPK 8
#define NLIM 4

constexpr int BM = 64, BN = 64, BK = 16;

// ------------- Gate GEMM, fp64 accumulation + sigmoid epilogue -------------
// scores[t][e] = sigmoid_f64( dot_f64(x[t,:], w[e,:]) )
__global__ __launch_bounds__(256) void gate_gemm_f64(
    const float* __restrict__ x, const float* __restrict__ w,
    double* __restrict__ scores) {
  __shared__ float Xs[BK][BM + 4];
  __shared__ float Ws[BK][BN + 4];
  const int tid = threadIdx.x;
  const int row0 = blockIdx.x * BM, col0 = blockIdx.y * BN;
  const int tr = tid >> 4, tc = tid & 15;  // 16x16 threads, 4x4 micro-tile

  double acc[4][4];
#pragma unroll
  for (int i = 0; i < 4; i++)
#pragma unroll
    for (int j = 0; j < 4; j++) acc[i][j] = 0.0;

  const int r = tid >> 2, c4 = (tid & 3) << 2;
  for (int k0 = 0; k0 < DDIM; k0 += BK) {
    float4 v = *reinterpret_cast<const float4*>(
        x + (size_t)(row0 + r) * DDIM + k0 + c4);
    Xs[c4 + 0][r] = v.x; Xs[c4 + 1][r] = v.y;
    Xs[c4 + 2][r] = v.z; Xs[c4 + 3][r] = v.w;
    float4 u = *reinterpret_cast<const float4*>(
        w + (size_t)(col0 + r) * DDIM + k0 + c4);
    Ws[c4 + 0][r] = u.x; Ws[c4 + 1][r] = u.y;
    Ws[c4 + 2][r] = u.z; Ws[c4 + 3][r] = u.w;
    __syncthreads();
#pragma unroll
    for (int k = 0; k < BK; k++) {
      float4 a = *reinterpret_cast<const float4*>(&Xs[k][tr * 4]);
      float4 b = *reinterpret_cast<const float4*>(&Ws[k][tc * 4]);
      double ad[4] = {(double)a.x, (double)a.y, (double)a.z, (double)a.w};
      double bd[4] = {(double)b.x, (double)b.y, (double)b.z, (double)b.w};
#pragma unroll
      for (int i = 0; i < 4; i++)
#pragma unroll
        for (int j = 0; j < 4; j++)
          acc[i][j] = fma(ad[i], bd[j], acc[i][j]);
    }
    __syncthreads();
  }
#pragma unroll
  for (int i = 0; i < 4; i++) {
    double o[4];
#pragma unroll
    for (int j = 0; j < 4; j++) o[j] = 1.0 / (1.0 + exp(-acc[i][j]));
    size_t base = (size_t)(row0 + tr * 4 + i) * NEXP + col0 + tc * 4;
    *reinterpret_cast<double2*>(scores + base) = make_double2(o[0], o[1]);
    *reinterpret_cast<double2*>(scores + base + 2) = make_double2(o[2], o[3]);
  }
}

// ---------------- zero counts ----------------
__global__ void zero_counts(float* __restrict__ c) { c[threadIdx.x] = 0.f; }

// ------------- router: all comparisons in fp64, one wave per token ---------
__global__ __launch_bounds__(256) void router_kernel(
    const double* __restrict__ scores, const float* __restrict__ bias,
    float* __restrict__ out_scores, float* __restrict__ out_sel,
    float* __restrict__ out_counts) {
  __shared__ int hist[NEXP];
  const int tid = threadIdx.x;
  hist[tid] = 0;
  __syncthreads();

  const int wave = tid >> 6, lane = tid & 63;
  const int t = blockIdx.x * 4 + wave;

  // lane owns experts 4*lane .. 4*lane+3 ; group g = lane>>3 (8 lanes/group)
  double s[4], c[4];
  {
    const double* p = scores + (size_t)t * NEXP + lane * 4;
    double2 v0 = *reinterpret_cast<const double2*>(p);
    double2 v1 = *reinterpret_cast<const double2*>(p + 2);
    s[0] = v0.x; s[1] = v0.y; s[2] = v1.x; s[3] = v1.y;
    float4 bv = *reinterpret_cast<const float4*>(bias + lane * 4);
    c[0] = s[0] + (double)bv.x; c[1] = s[1] + (double)bv.y;
    c[2] = s[2] + (double)bv.z; c[3] = s[3] + (double)bv.w;
  }

  // top-2 of my 4 biased scores
  double h1 = fmax(c[0], c[1]), l1 = fmin(c[0], c[1]);
  double h2 = fmax(c[2], c[3]), l2 = fmin(c[2], c[3]);
  double m1 = fmax(h1, h2);
  double m2 = fmax(fmin(h1, h2), fmax(l1, l2));
  // merge top-2 across the 8 lanes of the group (xor d=1,2,4 stays in-group)
#pragma unroll
  for (int d = 1; d <= 4; d <<= 1) {
    double om1 = __shfl_xor(m1, d);
    double om2 = __shfl_xor(m2, d);
    double n1 = fmax(m1, om1);
    double n2 = fmax(fmin(m1, om1), fmax(m2, om2));
    m1 = n1; m2 = n2;
  }
  double gscore = m1 + m2;

  // every lane gathers all 8 group scores
  double gs[8];
#pragma unroll
  for (int g = 0; g < 8; g++) gs[g] = __shfl(gscore, g * 8);
  const int gme = lane >> 3;
  int rank = 0;
#pragma unroll
  for (int h = 0; h < 8; h++)
    rank += (gs[h] > gs[gme]) || (gs[h] == gs[gme] && h < gme);
  const bool keep = rank < NLIM;  // top-4 groups, ties -> lower group index

  const double NEG = -HUGE_VAL;
  double v[4];
#pragma unroll
  for (int j = 0; j < 4; j++) v[j] = keep ? c[j] : NEG;

  // 8 iterations of wave-wide argmax (tie-break: lower expert index)
  double selS[TOPK];
  int selE[TOPK];
#pragma unroll
  for (int kk = 0; kk < TOPK; kk++) {
    double bvv = v[0];
    int bi = lane * 4;
#pragma unroll
    for (int j = 1; j < 4; j++)
      if (v[j] > bvv) { bvv = v[j]; bi = lane * 4 + j; }
#pragma unroll
    for (int d = 1; d <= 32; d <<= 1) {
      double ov = __shfl_xor(bvv, d);
      int oi = __shfl_xor(bi, d);
      if (ov > bvv || (ov == bvv && oi < bi)) { bvv = ov; bi = oi; }
    }
    selE[kk] = bi;
    int ol = bi >> 2, oj = bi & 3;
    double cand = (oj == 0) ? s[0] : (oj == 1) ? s[1] : (oj == 2) ? s[2] : s[3];
    selS[kk] = __shfl(cand, ol);  // unbiased sigmoid score of the winner
#pragma unroll
    for (int j = 0; j < 4; j++)
      if (lane == ol && j == oj) v[j] = NEG;
  }

  double denom = 1e-20;
#pragma unroll
  for (int kk = 0; kk < TOPK; kk++) denom += selS[kk];
  double scale = 2.5 / denom;

  if (lane == 0) {
    float4 o;
    o.x = (float)(selS[0] * scale); o.y = (float)(selS[1] * scale);
    o.z = (float)(selS[2] * scale); o.w = (float)(selS[3] * scale);
    *reinterpret_cast<float4*>(out_scores + (size_t)t * TOPK) = o;
    o.x = (float)(selS[4] * scale); o.y = (float)(selS[5] * scale);
    o.z = (float)(selS[6] * scale); o.w = (float)(selS[7] * scale);
    *reinterpret_cast<float4*>(out_scores + (size_t)t * TOPK + 4) = o;
    float4 e;
    e.x = (float)selE[0]; e.y = (float)selE[1];
    e.z = (float)selE[2]; e.w = (float)selE[3];
    *reinterpret_cast<float4*>(out_sel + (size_t)t * TOPK) = e;
    e.x = (float)selE[4]; e.y = (float)selE[5];
    e.z = (float)selE[6]; e.w = (float)selE[7];
    *reinterpret_cast<float4*>(out_sel + (size_t)t * TOPK + 4) = e;
#pragma unroll
    for (int kk = 0; kk < TOPK; kk++) atomicAdd(&hist[selE[kk]], 1);
  }
  __syncthreads();
  int hcount = hist[tid];
  if (hcount) atomicAdd(&out_counts[tid], (float)hcount);
}

extern "C" void kernel_launch(void* const* d_in, const int* in_sizes, int n_in,
                              void* d_out, int out_size, void* d_ws, size_t ws_size,
                              hipStream_t stream) {
  const float* x = (const float*)d_in[0];
  const float* w = (const float*)d_in[1];
  const float* bias = (const float*)d_in[2];
  float* out = (float*)d_out;
  float* out_scores = out;                     // 16384*8
  float* out_sel = out + T_TOK * TOPK;         // 16384*8 (indices as floats)
  float* out_counts = out + 2 * T_TOK * TOPK;  // 256
  double* scores = (double*)d_ws;              // 16384*256 fp64 = 32 MB

  dim3 g(T_TOK / BM, NEXP / BN);
  gate_gemm_f64<<<g, 256, 0, stream>>>(x, w, scores);
  zero_counts<<<1, 256, 0, stream>>>(out_counts);
  router_kernel<<<T_TOK / 4, 256, 0, stream>>>(scores, bias, out_scores,
                                               out_sel, out_counts);
}

// Round 3
// 405.245 us; speedup vs baseline: 1.3238x; 1.3238x over previous
//
#include <hip/hip_runtime.h>
#include <math.h>

#define T_TOK 16384
#define DDIM 2048
#define NEXP 256
#define TOPK 8
#define NLIM 4

constexpr float EPSC = 1e-5f;  // score-space fp32 uncertainty bound

// ---------------- K1: fp32 gate GEMM + sigmoid ----------------
constexpr int BM = 128, BN = 64, BK = 32;
__global__ __launch_bounds__(256) void gate_gemm_f32(
    const float* __restrict__ x, const float* __restrict__ w,
    float* __restrict__ scores) {
  __shared__ float Xs[BK][BM + 4];
  __shared__ float Ws[BK][BN + 4];
  const int tid = threadIdx.x;
  const int row0 = blockIdx.x * BM, col0 = blockIdx.y * BN;
  const int tr = tid >> 4, tc = tid & 15;  // 16x16 threads, 8x4 micro-tile

  float acc[8][4];
#pragma unroll
  for (int i = 0; i < 8; i++)
#pragma unroll
    for (int j = 0; j < 4; j++) acc[i][j] = 0.f;

  for (int k0 = 0; k0 < DDIM; k0 += BK) {
#pragma unroll
    for (int i = 0; i < 4; i++) {
      int fid = tid + i * 256;
      int r = fid >> 3, c4 = (fid & 7) << 2;
      float4 v = *reinterpret_cast<const float4*>(
          x + (size_t)(row0 + r) * DDIM + k0 + c4);
      Xs[c4 + 0][r] = v.x; Xs[c4 + 1][r] = v.y;
      Xs[c4 + 2][r] = v.z; Xs[c4 + 3][r] = v.w;
    }
#pragma unroll
    for (int i = 0; i < 2; i++) {
      int fid = tid + i * 256;
      int r = fid >> 3, c4 = (fid & 7) << 2;
      float4 v = *reinterpret_cast<const float4*>(
          w + (size_t)(col0 + r) * DDIM + k0 + c4);
      Ws[c4 + 0][r] = v.x; Ws[c4 + 1][r] = v.y;
      Ws[c4 + 2][r] = v.z; Ws[c4 + 3][r] = v.w;
    }
    __syncthreads();
#pragma unroll
    for (int k = 0; k < BK; k++) {
      float a[8], b[4];
      *reinterpret_cast<float4*>(&a[0]) =
          *reinterpret_cast<const float4*>(&Xs[k][tr * 8]);
      *reinterpret_cast<float4*>(&a[4]) =
          *reinterpret_cast<const float4*>(&Xs[k][tr * 8 + 4]);
      *reinterpret_cast<float4*>(&b[0]) =
          *reinterpret_cast<const float4*>(&Ws[k][tc * 4]);
#pragma unroll
      for (int i = 0; i < 8; i++)
#pragma unroll
        for (int j = 0; j < 4; j++) acc[i][j] = fmaf(a[i], b[j], acc[i][j]);
    }
    __syncthreads();
  }
#pragma unroll
  for (int i = 0; i < 8; i++) {
    float4 o;
    o.x = 1.f / (1.f + expf(-acc[i][0]));
    o.y = 1.f / (1.f + expf(-acc[i][1]));
    o.z = 1.f / (1.f + expf(-acc[i][2]));
    o.w = 1.f / (1.f + expf(-acc[i][3]));
    *reinterpret_cast<float4*>(
        scores + (size_t)(row0 + tr * 8 + i) * NEXP + col0 + tc * 4) = o;
  }
}

// ---------------- zero counts + worklist counter ----------------
__global__ void zero_init(float* __restrict__ c, int* __restrict__ wl_count) {
  c[threadIdx.x] = 0.f;
  if (threadIdx.x == 0) *wl_count = 0;
}

// ------- K2: fp32 router with margin certification; flag close calls -------
__global__ __launch_bounds__(256) void router_flag(
    const float* __restrict__ scores, const float* __restrict__ bias,
    float* __restrict__ out_scores, float* __restrict__ out_sel,
    float* __restrict__ out_counts, int* __restrict__ wl_count,
    int* __restrict__ wl) {
  __shared__ int hist[NEXP];
  const int tid = threadIdx.x;
  hist[tid] = 0;
  __syncthreads();

  const int wave = tid >> 6, lane = tid & 63;
  const int t = blockIdx.x * 4 + wave;

  float4 sv = *reinterpret_cast<const float4*>(scores + (size_t)t * NEXP + lane * 4);
  float4 bv = *reinterpret_cast<const float4*>(bias + lane * 4);
  float s[4] = {sv.x, sv.y, sv.z, sv.w};
  float c[4] = {sv.x + bv.x, sv.y + bv.y, sv.z + bv.z, sv.w + bv.w};

  // top-2 of my 4 biased scores, merge across group (8 lanes)
  float h1 = fmaxf(c[0], c[1]);
  float h2 = fmaxf(c[2], c[3]);
  float m1 = fmaxf(h1, h2);
  float m2 = fmaxf(fminf(h1, h2), fmaxf(fminf(c[0], c[1]), fminf(c[2], c[3])));
#pragma unroll
  for (int d = 1; d <= 4; d <<= 1) {
    float om1 = __shfl_xor(m1, d);
    float om2 = __shfl_xor(m2, d);
    float n1 = fmaxf(m1, om1);
    float n2 = fmaxf(fminf(m1, om1), fmaxf(m2, om2));
    m1 = n1; m2 = n2;
  }
  float gscore = m1 + m2;

  float gs[8];
#pragma unroll
  for (int g = 0; g < 8; g++) gs[g] = __shfl(gscore, g * 8);
  const int gme = lane >> 3;
  int rank = 0;
#pragma unroll
  for (int h = 0; h < 8; h++)
    rank += (gs[h] > gs[gme]) || (gs[h] == gs[gme] && h < gme);
  const bool keep = rank < NLIM;

  // group margin: gap between 4th and 5th ranked group scores
  float v4 = 0.f, v5 = 0.f;
#pragma unroll
  for (int g = 0; g < 8; g++) {
    int rk = 0;
#pragma unroll
    for (int h = 0; h < 8; h++)
      rk += (gs[h] > gs[g]) || (gs[h] == gs[g] && h < g);
    if (rk == 3) v4 = gs[g];
    if (rk == 4) v5 = gs[g];
  }
  bool flag = (v4 - v5) < 8.f * EPSC;

  float v[4];
#pragma unroll
  for (int j = 0; j < 4; j++) v[j] = keep ? c[j] : -INFINITY;

  // 9 extractions: top-8 + 9th for the boundary margin
  float selS[TOPK];
  int selE[TOPK];
  float prevB = 0.f;
#pragma unroll
  for (int kk = 0; kk < TOPK + 1; kk++) {
    float bvv = v[0];
    int bi = lane * 4;
#pragma unroll
    for (int j = 1; j < 4; j++)
      if (v[j] > bvv) { bvv = v[j]; bi = lane * 4 + j; }
#pragma unroll
    for (int d = 1; d <= 32; d <<= 1) {
      float ov = __shfl_xor(bvv, d);
      int oi = __shfl_xor(bi, d);
      if (ov > bvv || (ov == bvv && oi < bi)) { bvv = ov; bi = oi; }
    }
    int ol = bi >> 2, oj = bi & 3;
    if (kk < TOPK) {
      selE[kk] = bi;
      float cand = (oj == 0) ? s[0] : (oj == 1) ? s[1] : (oj == 2) ? s[2] : s[3];
      selS[kk] = __shfl(cand, ol);
    }
    if (kk > 0 && (prevB - bvv) < 2.f * EPSC) flag = true;
    prevB = bvv;
#pragma unroll
    for (int j = 0; j < 4; j++)
      if (lane == ol && j == oj) v[j] = -INFINITY;
  }

  if (!flag) {
    float denom = 1e-20f;
#pragma unroll
    for (int kk = 0; kk < TOPK; kk++) denom += selS[kk];
    float scale = 2.5f / denom;
    if (lane == 0) {
      float4 o;
      o.x = selS[0] * scale; o.y = selS[1] * scale;
      o.z = selS[2] * scale; o.w = selS[3] * scale;
      *reinterpret_cast<float4*>(out_scores + (size_t)t * TOPK) = o;
      o.x = selS[4] * scale; o.y = selS[5] * scale;
      o.z = selS[6] * scale; o.w = selS[7] * scale;
      *reinterpret_cast<float4*>(out_scores + (size_t)t * TOPK + 4) = o;
      float4 e;
      e.x = (float)selE[0]; e.y = (float)selE[1];
      e.z = (float)selE[2]; e.w = (float)selE[3];
      *reinterpret_cast<float4*>(out_sel + (size_t)t * TOPK) = e;
      e.x = (float)selE[4]; e.y = (float)selE[5];
      e.z = (float)selE[6]; e.w = (float)selE[7];
      *reinterpret_cast<float4*>(out_sel + (size_t)t * TOPK + 4) = e;
#pragma unroll
      for (int kk = 0; kk < TOPK; kk++) atomicAdd(&hist[selE[kk]], 1);
    }
  } else if (lane == 0) {
    int i = atomicAdd(wl_count, 1);
    wl[i] = t;
  }
  __syncthreads();
  int hcount = hist[tid];
  if (hcount) atomicAdd(&out_counts[tid], (float)hcount);
}

// ------- K3: f64 recompute + exact selection for flagged tokens -------
__global__ __launch_bounds__(256) void fixup_f64(
    const float* __restrict__ x, const float* __restrict__ w,
    const float* __restrict__ bias, float* __restrict__ out_scores,
    float* __restrict__ out_sel, float* __restrict__ out_counts,
    const int* __restrict__ wl_count, const int* __restrict__ wl) {
  __shared__ float xs[DDIM];
  __shared__ double sc[NEXP];
  const int n = *wl_count;
  const int tid = threadIdx.x;

  for (int it = blockIdx.x; it < n; it += gridDim.x) {
    const int t = wl[it];
#pragma unroll
    for (int i = 0; i < 2; i++)
      reinterpret_cast<float4*>(xs)[tid + i * 256] =
          reinterpret_cast<const float4*>(x + (size_t)t * DDIM)[tid + i * 256];
    __syncthreads();

    const float* wr = w + (size_t)tid * DDIM;
    double a0 = 0, a1 = 0, a2 = 0, a3 = 0;
    for (int k = 0; k < DDIM; k += 8) {
      float4 w0 = *reinterpret_cast<const float4*>(wr + k);
      float4 w1 = *reinterpret_cast<const float4*>(wr + k + 4);
      float4 x0 = *reinterpret_cast<const float4*>(xs + k);
      float4 x1 = *reinterpret_cast<const float4*>(xs + k + 4);
      a0 = fma((double)x0.x, (double)w0.x, a0);
      a1 = fma((double)x0.y, (double)w0.y, a1);
      a2 = fma((double)x0.z, (double)w0.z, a2);
      a3 = fma((double)x0.w, (double)w0.w, a3);
      a0 = fma((double)x1.x, (double)w1.x, a0);
      a1 = fma((double)x1.y, (double)w1.y, a1);
      a2 = fma((double)x1.z, (double)w1.z, a2);
      a3 = fma((double)x1.w, (double)w1.w, a3);
    }
    double logit = (a0 + a1) + (a2 + a3);
    sc[tid] = 1.0 / (1.0 + exp(-logit));
    __syncthreads();

    if (tid < 64) {
      const int lane = tid;
      double s[4], c[4];
      s[0] = sc[lane * 4 + 0]; s[1] = sc[lane * 4 + 1];
      s[2] = sc[lane * 4 + 2]; s[3] = sc[lane * 4 + 3];
      float4 bv = *reinterpret_cast<const float4*>(bias + lane * 4);
      c[0] = s[0] + (double)bv.x; c[1] = s[1] + (double)bv.y;
      c[2] = s[2] + (double)bv.z; c[3] = s[3] + (double)bv.w;

      double h1 = fmax(c[0], c[1]), l1 = fmin(c[0], c[1]);
      double h2 = fmax(c[2], c[3]), l2 = fmin(c[2], c[3]);
      double m1 = fmax(h1, h2);
      double m2 = fmax(fmin(h1, h2), fmax(l1, l2));
#pragma unroll
      for (int d = 1; d <= 4; d <<= 1) {
        double om1 = __shfl_xor(m1, d);
        double om2 = __shfl_xor(m2, d);
        double n1 = fmax(m1, om1);
        double n2 = fmax(fmin(m1, om1), fmax(m2, om2));
        m1 = n1; m2 = n2;
      }
      double gscore = m1 + m2;
      double gsv[8];
#pragma unroll
      for (int g = 0; g < 8; g++) gsv[g] = __shfl(gscore, g * 8);
      const int gme = lane >> 3;
      int rank = 0;
#pragma unroll
      for (int h = 0; h < 8; h++)
        rank += (gsv[h] > gsv[gme]) || (gsv[h] == gsv[gme] && h < gme);
      const bool keep = rank < NLIM;

      const double NEG = -HUGE_VAL;
      double v[4];
#pragma unroll
      for (int j = 0; j < 4; j++) v[j] = keep ? c[j] : NEG;

      double selS[TOPK];
      int selE[TOPK];
#pragma unroll
      for (int kk = 0; kk < TOPK; kk++) {
        double bvv = v[0];
        int bi = lane * 4;
#pragma unroll
        for (int j = 1; j < 4; j++)
          if (v[j] > bvv) { bvv = v[j]; bi = lane * 4 + j; }
#pragma unroll
        for (int d = 1; d <= 32; d <<= 1) {
          double ov = __shfl_xor(bvv, d);
          int oi = __shfl_xor(bi, d);
          if (ov > bvv || (ov == bvv && oi < bi)) { bvv = ov; bi = oi; }
        }
        selE[kk] = bi;
        int ol = bi >> 2, oj = bi & 3;
        double cand = (oj == 0) ? s[0] : (oj == 1) ? s[1] : (oj == 2) ? s[2] : s[3];
        selS[kk] = __shfl(cand, ol);
#pragma unroll
        for (int j = 0; j < 4; j++)
          if (lane == ol && j == oj) v[j] = NEG;
      }

      double denom = 1e-20;
#pragma unroll
      for (int kk = 0; kk < TOPK; kk++) denom += selS[kk];
      double scale = 2.5 / denom;

      if (lane == 0) {
        float4 o;
        o.x = (float)(selS[0] * scale); o.y = (float)(selS[1] * scale);
        o.z = (float)(selS[2] * scale); o.w = (float)(selS[3] * scale);
        *reinterpret_cast<float4*>(out_scores + (size_t)t * TOPK) = o;
        o.x = (float)(selS[4] * scale); o.y = (float)(selS[5] * scale);
        o.z = (float)(selS[6] * scale); o.w = (float)(selS[7] * scale);
        *reinterpret_cast<float4*>(out_scores + (size_t)t * TOPK + 4) = o;
        float4 e;
        e.x = (float)selE[0]; e.y = (float)selE[1];
        e.z = (float)selE[2]; e.w = (float)selE[3];
        *reinterpret_cast<float4*>(out_sel + (size_t)t * TOPK) = e;
        e.x = (float)selE[4]; e.y = (float)selE[5];
        e.z = (float)selE[6]; e.w = (float)selE[7];
        *reinterpret_cast<float4*>(out_sel + (size_t)t * TOPK + 4) = e;
#pragma unroll
        for (int kk = 0; kk < TOPK; kk++)
          atomicAdd(&out_counts[selE[kk]], 1.0f);
      }
    }
    __syncthreads();
  }
}

extern "C" void kernel_launch(void* const* d_in, const int* in_sizes, int n_in,
                              void* d_out, int out_size, void* d_ws, size_t ws_size,
                              hipStream_t stream) {
  const float* x = (const float*)d_in[0];
  const float* w = (const float*)d_in[1];
  const float* bias = (const float*)d_in[2];
  float* out = (float*)d_out;
  float* out_scores = out;
  float* out_sel = out + T_TOK * TOPK;
  float* out_counts = out + 2 * T_TOK * TOPK;

  float* scores = (float*)d_ws;  // 16 MB fp32
  int* wl_count = (int*)((char*)d_ws + (size_t)T_TOK * NEXP * 4);
  int* wl = wl_count + 4;

  zero_init<<<1, 256, 0, stream>>>(out_counts, wl_count);
  dim3 g(T_TOK / BM, NEXP / BN);
  gate_gemm_f32<<<g, 256, 0, stream>>>(x, w, scores);
  router_flag<<<T_TOK / 4, 256, 0, stream>>>(scores, bias, out_scores,
                                             out_sel, out_counts, wl_count, wl);
  fixup_f64<<<1024, 256, 0, stream>>>(x, w, bias, out_scores, out_sel,
                                      out_counts, wl_count, wl);
}

// Round 5
// 250.444 us; speedup vs baseline: 2.1421x; 1.6181x over previous
//
#include <hip/hip_runtime.h>
#include <math.h>

#define T_TOK 16384
#define DDIM 2048
#define NEXP 256
#define TOPK 8
#define NLIM 4

constexpr float EPSC = 1e-5f;         // certified score-space error bound
constexpr float SCL = 1.f / 4096.f;   // undo x*16, w*256 scaling

typedef _Float16 half4v __attribute__((ext_vector_type(4)));
typedef _Float16 half8v __attribute__((ext_vector_type(8)));
typedef float f32x4 __attribute__((ext_vector_type(4)));

// ---------------- K0: zero logits + convert w to fp16 hi/lo + init ---------
__global__ __launch_bounds__(256) void prep(
    const float* __restrict__ w, float* __restrict__ logits,
    _Float16* __restrict__ wh, _Float16* __restrict__ wlo,
    float* __restrict__ counts, int* __restrict__ wl_count) {
  int gid = blockIdx.x * 256 + threadIdx.x;  // 2048 blocks -> 524288 threads
  float4 z = make_float4(0.f, 0.f, 0.f, 0.f);
  reinterpret_cast<float4*>(logits)[gid * 2] = z;
  reinterpret_cast<float4*>(logits)[gid * 2 + 1] = z;
  float W = w[gid] * 256.f;
  _Float16 h = (_Float16)W;
  wh[gid] = h;
  wlo[gid] = (_Float16)(W - (float)h);
  if (blockIdx.x == 0) {
    counts[threadIdx.x] = 0.f;
    if (threadIdx.x == 0) *wl_count = 0;
  }
}

// ---------------- K1: MFMA gate GEMM (fp16 split-2, 3 products) ------------
constexpr int BM = 128, BN = 128, BK = 32;
__global__ __launch_bounds__(256) void gate_gemm_mfma(
    const float* __restrict__ x, const _Float16* __restrict__ wh,
    const _Float16* __restrict__ wlo, float* __restrict__ logits) {
  __shared__ _Float16 Ah[128][40], Al[128][40];  // +8 pad, rows 16B-multiple
  __shared__ _Float16 Bh[128][40], Bl[128][40];
  const int tid = threadIdx.x;
  const int bid = blockIdx.x;
  const int sk = bid & 1, nb = (bid >> 1) & 1, mb = bid >> 2;
  const int row0 = mb * BM, col0 = nb * BN, kbase = sk * 1024;
  const int wave = tid >> 6, lane = tid & 63;
  const int m0 = (wave >> 1) * 64, n0 = (wave & 1) * 64;

  f32x4 acc[4][4];
#pragma unroll
  for (int i = 0; i < 4; i++)
#pragma unroll
    for (int j = 0; j < 4; j++) acc[i][j] = (f32x4){0.f, 0.f, 0.f, 0.f};

  for (int k0 = kbase; k0 < kbase + 1024; k0 += BK) {
    // stage A: 128x32 fp32 -> convert to fp16 hi/lo (x scaled by 16)
#pragma unroll
    for (int i = 0; i < 4; i++) {
      int f = tid + i * 256;
      int r = f >> 3, c4 = (f & 7) << 2;
      float4 v = *reinterpret_cast<const float4*>(
          x + (size_t)(row0 + r) * DDIM + k0 + c4);
      float X0 = v.x * 16.f, X1 = v.y * 16.f, X2 = v.z * 16.f, X3 = v.w * 16.f;
      _Float16 h0 = (_Float16)X0, h1 = (_Float16)X1;
      _Float16 h2 = (_Float16)X2, h3 = (_Float16)X3;
      half4v hv = {h0, h1, h2, h3};
      half4v lv = {(_Float16)(X0 - (float)h0), (_Float16)(X1 - (float)h1),
                   (_Float16)(X2 - (float)h2), (_Float16)(X3 - (float)h3)};
      *reinterpret_cast<half4v*>(&Ah[r][c4]) = hv;
      *reinterpret_cast<half4v*>(&Al[r][c4]) = lv;
    }
    // stage B: 128x32 fp16 hi/lo (pre-converted)
#pragma unroll
    for (int i = 0; i < 2; i++) {
      int f = tid + i * 256;
      int c = f >> 2, kc = (f & 3) << 3;
      size_t g = (size_t)(col0 + c) * DDIM + k0 + kc;
      *reinterpret_cast<half8v*>(&Bh[c][kc]) =
          *reinterpret_cast<const half8v*>(wh + g);
      *reinterpret_cast<half8v*>(&Bl[c][kc]) =
          *reinterpret_cast<const half8v*>(wlo + g);
    }
    __syncthreads();

    // compute: 16x16x32 MFMA, one K=32 step
    {
      const int koff = (lane >> 4) * 8;
      half8v ah[4], al[4], bh[4], bl[4];
#pragma unroll
      for (int mf = 0; mf < 4; mf++) {
        int r = m0 + mf * 16 + (lane & 15);
        ah[mf] = *reinterpret_cast<half8v*>(&Ah[r][koff]);
        al[mf] = *reinterpret_cast<half8v*>(&Al[r][koff]);
      }
#pragma unroll
      for (int nf = 0; nf < 4; nf++) {
        int c = n0 + nf * 16 + (lane & 15);
        bh[nf] = *reinterpret_cast<half8v*>(&Bh[c][koff]);
        bl[nf] = *reinterpret_cast<half8v*>(&Bl[c][koff]);
      }
#pragma unroll
      for (int mf = 0; mf < 4; mf++)
#pragma unroll
        for (int nf = 0; nf < 4; nf++) {
          acc[mf][nf] = __builtin_amdgcn_mfma_f32_16x16x32_f16(
              ah[mf], bh[nf], acc[mf][nf], 0, 0, 0);
          acc[mf][nf] = __builtin_amdgcn_mfma_f32_16x16x32_f16(
              ah[mf], bl[nf], acc[mf][nf], 0, 0, 0);
          acc[mf][nf] = __builtin_amdgcn_mfma_f32_16x16x32_f16(
              al[mf], bh[nf], acc[mf][nf], 0, 0, 0);
        }
    }
    __syncthreads();
  }
  // epilogue: atomic-accumulate scaled logits (split-K partial)
#pragma unroll
  for (int mf = 0; mf < 4; mf++)
#pragma unroll
    for (int nf = 0; nf < 4; nf++)
#pragma unroll
      for (int reg = 0; reg < 4; reg++) {
        int r = m0 + mf * 16 + (lane >> 4) * 4 + reg;
        int c = n0 + nf * 16 + (lane & 15);
        atomicAdd(&logits[(size_t)(row0 + r) * NEXP + col0 + c],
                  acc[mf][nf][reg]);
      }
}

// ------- K2: fp32 router with margin certification; flag close calls -------
__global__ __launch_bounds__(256) void router_flag(
    const float* __restrict__ logits, const float* __restrict__ bias,
    float* __restrict__ out_scores, float* __restrict__ out_sel,
    float* __restrict__ out_counts, int* __restrict__ wl_count,
    int* __restrict__ wlist) {
  __shared__ int hist[NEXP];
  const int tid = threadIdx.x;
  hist[tid] = 0;
  __syncthreads();

  const int wave = tid >> 6, lane = tid & 63;
  const int t = blockIdx.x * 4 + wave;

  float4 lg = *reinterpret_cast<const float4*>(logits + (size_t)t * NEXP + lane * 4);
  float4 bv = *reinterpret_cast<const float4*>(bias + lane * 4);
  float s[4];
  s[0] = 1.f / (1.f + expf(-lg.x * SCL));
  s[1] = 1.f / (1.f + expf(-lg.y * SCL));
  s[2] = 1.f / (1.f + expf(-lg.z * SCL));
  s[3] = 1.f / (1.f + expf(-lg.w * SCL));
  float c[4] = {s[0] + bv.x, s[1] + bv.y, s[2] + bv.z, s[3] + bv.w};

  // top-2 of my 4 biased scores, merge across group (8 lanes)
  float h1 = fmaxf(c[0], c[1]);
  float h2 = fmaxf(c[2], c[3]);
  float m1 = fmaxf(h1, h2);
  float m2 = fmaxf(fminf(h1, h2), fmaxf(fminf(c[0], c[1]), fminf(c[2], c[3])));
#pragma unroll
  for (int d = 1; d <= 4; d <<= 1) {
    float om1 = __shfl_xor(m1, d);
    float om2 = __shfl_xor(m2, d);
    float n1 = fmaxf(m1, om1);
    float n2 = fmaxf(fminf(m1, om1), fmaxf(m2, om2));
    m1 = n1; m2 = n2;
  }
  float gscore = m1 + m2;

  float gs[8];
#pragma unroll
  for (int g = 0; g < 8; g++) gs[g] = __shfl(gscore, g * 8);
  const int gme = lane >> 3;
  int rank = 0;
#pragma unroll
  for (int h = 0; h < 8; h++)
    rank += (gs[h] > gs[gme]) || (gs[h] == gs[gme] && h < gme);
  const bool keep = rank < NLIM;

  // group margin: 4th vs 5th ranked group scores
  float v4 = 0.f, v5 = 0.f;
#pragma unroll
  for (int g = 0; g < 8; g++) {
    int rk = 0;
#pragma unroll
    for (int h = 0; h < 8; h++)
      rk += (gs[h] > gs[g]) || (gs[h] == gs[g] && h < g);
    if (rk == 3) v4 = gs[g];
    if (rk == 4) v5 = gs[g];
  }
  bool flag = (v4 - v5) < 8.f * EPSC;

  float v[4];
#pragma unroll
  for (int j = 0; j < 4; j++) v[j] = keep ? c[j] : -INFINITY;

  float selS[TOPK];
  int selE[TOPK];
  float prevB = 0.f;
#pragma unroll
  for (int kk = 0; kk < TOPK + 1; kk++) {
    float bvv = v[0];
    int bi = lane * 4;
#pragma unroll
    for (int j = 1; j < 4; j++)
      if (v[j] > bvv) { bvv = v[j]; bi = lane * 4 + j; }
#pragma unroll
    for (int d = 1; d <= 32; d <<= 1) {
      float ov = __shfl_xor(bvv, d);
      int oi = __shfl_xor(bi, d);
      if (ov > bvv || (ov == bvv && oi < bi)) { bvv = ov; bi = oi; }
    }
    int ol = bi >> 2, oj = bi & 3;
    if (kk < TOPK) {
      selE[kk] = bi;
      float cand = (oj == 0) ? s[0] : (oj == 1) ? s[1] : (oj == 2) ? s[2] : s[3];
      selS[kk] = __shfl(cand, ol);
    }
    if (kk > 0 && (prevB - bvv) < 2.f * EPSC) flag = true;
    prevB = bvv;
#pragma unroll
    for (int j = 0; j < 4; j++)
      if (lane == ol && j == oj) v[j] = -INFINITY;
  }

  if (!flag) {
    float denom = 1e-20f;
#pragma unroll
    for (int kk = 0; kk < TOPK; kk++) denom += selS[kk];
    float scale = 2.5f / denom;
    if (lane == 0) {
      float4 o;
      o.x = selS[0] * scale; o.y = selS[1] * scale;
      o.z = selS[2] * scale; o.w = selS[3] * scale;
      *reinterpret_cast<float4*>(out_scores + (size_t)t * TOPK) = o;
      o.x = selS[4] * scale; o.y = selS[5] * scale;
      o.z = selS[6] * scale; o.w = selS[7] * scale;
      *reinterpret_cast<float4*>(out_scores + (size_t)t * TOPK + 4) = o;
      float4 e;
      e.x = (float)selE[0]; e.y = (float)selE[1];
      e.z = (float)selE[2]; e.w = (float)selE[3];
      *reinterpret_cast<float4*>(out_sel + (size_t)t * TOPK) = e;
      e.x = (float)selE[4]; e.y = (float)selE[5];
      e.z = (float)selE[6]; e.w = (float)selE[7];
      *reinterpret_cast<float4*>(out_sel + (size_t)t * TOPK + 4) = e;
#pragma unroll
      for (int kk = 0; kk < TOPK; kk++) atomicAdd(&hist[selE[kk]], 1);
    }
  } else if (lane == 0) {
    int i = atomicAdd(wl_count, 1);
    wlist[i] = t;
  }
  __syncthreads();
  int hcount = hist[tid];
  if (hcount) atomicAdd(&out_counts[tid], (float)hcount);
}

// ------- K3: f64 recompute + exact selection for flagged tokens -------
__global__ __launch_bounds__(256) void fixup_f64(
    const float* __restrict__ x, const float* __restrict__ w,
    const float* __restrict__ bias, float* __restrict__ out_scores,
    float* __restrict__ out_sel, float* __restrict__ out_counts,
    const int* __restrict__ wl_count, const int* __restrict__ wlist) {
  __shared__ float xs[DDIM];
  __shared__ double sc[NEXP];
  const int n = *wl_count;
  const int tid = threadIdx.x;

  for (int it = blockIdx.x; it < n; it += gridDim.x) {
    const int t = wlist[it];
#pragma unroll
    for (int i = 0; i < 2; i++)
      reinterpret_cast<float4*>(xs)[tid + i * 256] =
          reinterpret_cast<const float4*>(x + (size_t)t * DDIM)[tid + i * 256];
    __syncthreads();

    const float* wr = w + (size_t)tid * DDIM;
    double a0 = 0, a1 = 0, a2 = 0, a3 = 0;
    for (int k = 0; k < DDIM; k += 8) {
      float4 w0 = *reinterpret_cast<const float4*>(wr + k);
      float4 w1 = *reinterpret_cast<const float4*>(wr + k + 4);
      float4 x0 = *reinterpret_cast<const float4*>(xs + k);
      float4 x1 = *reinterpret_cast<const float4*>(xs + k + 4);
      a0 = fma((double)x0.x, (double)w0.x, a0);
      a1 = fma((double)x0.y, (double)w0.y, a1);
      a2 = fma((double)x0.z, (double)w0.z, a2);
      a3 = fma((double)x0.w, (double)w0.w, a3);
      a0 = fma((double)x1.x, (double)w1.x, a0);
      a1 = fma((double)x1.y, (double)w1.y, a1);
      a2 = fma((double)x1.z, (double)w1.z, a2);
      a3 = fma((double)x1.w, (double)w1.w, a3);
    }
    double logit = (a0 + a1) + (a2 + a3);
    sc[tid] = 1.0 / (1.0 + exp(-logit));
    __syncthreads();

    if (tid < 64) {
      const int lane = tid;
      double s[4], c[4];
      s[0] = sc[lane * 4 + 0]; s[1] = sc[lane * 4 + 1];
      s[2] = sc[lane * 4 + 2]; s[3] = sc[lane * 4 + 3];
      float4 bv = *reinterpret_cast<const float4*>(bias + lane * 4);
      c[0] = s[0] + (double)bv.x; c[1] = s[1] + (double)bv.y;
      c[2] = s[2] + (double)bv.z; c[3] = s[3] + (double)bv.w;

      double h1 = fmax(c[0], c[1]), l1 = fmin(c[0], c[1]);
      double h2 = fmax(c[2], c[3]), l2 = fmin(c[2], c[3]);
      double m1 = fmax(h1, h2);
      double m2 = fmax(fmin(h1, h2), fmax(l1, l2));
#pragma unroll
      for (int d = 1; d <= 4; d <<= 1) {
        double om1 = __shfl_xor(m1, d);
        double om2 = __shfl_xor(m2, d);
        double n1 = fmax(m1, om1);
        double n2 = fmax(fmin(m1, om1), fmax(m2, om2));
        m1 = n1; m2 = n2;
      }
      double gscore = m1 + m2;
      double gsv[8];
#pragma unroll
      for (int g = 0; g < 8; g++) gsv[g] = __shfl(gscore, g * 8);
      const int gme = lane >> 3;
      int rank = 0;
#pragma unroll
      for (int h = 0; h < 8; h++)
        rank += (gsv[h] > gsv[gme]) || (gsv[h] == gsv[gme] && h < gme);
      const bool keep = rank < NLIM;

      const double NEG = -HUGE_VAL;
      double v[4];
#pragma unroll
      for (int j = 0; j < 4; j++) v[j] = keep ? c[j] : NEG;

      double selS[TOPK];
      int selE[TOPK];
#pragma unroll
      for (int kk = 0; kk < TOPK; kk++) {
        double bvv = v[0];
        int bi = lane * 4;
#pragma unroll
        for (int j = 1; j < 4; j++)
          if (v[j] > bvv) { bvv = v[j]; bi = lane * 4 + j; }
#pragma unroll
        for (int d = 1; d <= 32; d <<= 1) {
          double ov = __shfl_xor(bvv, d);
          int oi = __shfl_xor(bi, d);
          if (ov > bvv || (ov == bvv && oi < bi)) { bvv = ov; bi = oi; }
        }
        selE[kk] = bi;
        int ol = bi >> 2, oj = bi & 3;
        double cand = (oj == 0) ? s[0] : (oj == 1) ? s[1] : (oj == 2) ? s[2] : s[3];
        selS[kk] = __shfl(cand, ol);
#pragma unroll
        for (int j = 0; j < 4; j++)
          if (lane == ol && j == oj) v[j] = NEG;
      }

      double denom = 1e-20;
#pragma unroll
      for (int kk = 0; kk < TOPK; kk++) denom += selS[kk];
      double scale = 2.5 / denom;

      if (lane == 0) {
        float4 o;
        o.x = (float)(selS[0] * scale); o.y = (float)(selS[1] * scale);
        o.z = (float)(selS[2] * scale); o.w = (float)(selS[3] * scale);
        *reinterpret_cast<float4*>(out_scores + (size_t)t * TOPK) = o;
        o.x = (float)(selS[4] * scale); o.y = (float)(selS[5] * scale);
        o.z = (float)(selS[6] * scale); o.w = (float)(selS[7] * scale);
        *reinterpret_cast<float4*>(out_scores + (size_t)t * TOPK + 4) = o;
        float4 e;
        e.x = (float)selE[0]; e.y = (float)selE[1];
        e.z = (float)selE[2]; e.w = (float)selE[3];
        *reinterpret_cast<float4*>(out_sel + (size_t)t * TOPK) = e;
        e.x = (float)selE[4]; e.y = (float)selE[5];
        e.z = (float)selE[6]; e.w = (float)selE[7];
        *reinterpret_cast<float4*>(out_sel + (size_t)t * TOPK + 4) = e;
#pragma unroll
        for (int kk = 0; kk < TOPK; kk++)
          atomicAdd(&out_counts[selE[kk]], 1.0f);
      }
    }
    __syncthreads();
  }
}

extern "C" void kernel_launch(void* const* d_in, const int* in_sizes, int n_in,
                              void* d_out, int out_size, void* d_ws, size_t ws_size,
                              hipStream_t stream) {
  const float* x = (const float*)d_in[0];
  const float* w = (const float*)d_in[1];
  const float* bias = (const float*)d_in[2];
  float* out = (float*)d_out;
  float* out_scores = out;
  float* out_sel = out + T_TOK * TOPK;
  float* out_counts = out + 2 * T_TOK * TOPK;

  char* ws = (char*)d_ws;
  float* logits = (float*)ws;                                   // 16 MB
  _Float16* wh = (_Float16*)(ws + (size_t)16 * 1024 * 1024);    // 1 MB
  _Float16* wlo = (_Float16*)(ws + (size_t)17 * 1024 * 1024);   // 1 MB
  int* wl_count = (int*)(ws + (size_t)18 * 1024 * 1024);
  int* wlist = wl_count + 16;

  prep<<<2048, 256, 0, stream>>>(w, logits, wh, wlo, out_counts, wl_count);
  gate_gemm_mfma<<<512, 256, 0, stream>>>(x, wh, wlo, logits);
  router_flag<<<T_TOK / 4, 256, 0, stream>>>(logits, bias, out_scores,
                                             out_sel, out_counts, wl_count, wlist);
  fixup_f64<<<2048, 256, 0, stream>>>(x, w, bias, out_scores, out_sel,
                                      out_counts, wl_count, wlist);
}

// Round 6
// 235.617 us; speedup vs baseline: 2.2768x; 1.0629x over previous
//
#include <hip/hip_runtime.h>
#include <math.h>

#define T_TOK 16384
#define DDIM 2048
#define NEXP 256
#define TOPK 8
#define NLIM 4

constexpr float EPSC = 1e-5f;         // certified score-space error bound
constexpr float SCL = 1.f / 4096.f;   // undo x*16, w*256 scaling

typedef _Float16 half4v __attribute__((ext_vector_type(4)));
typedef _Float16 half8v __attribute__((ext_vector_type(8)));
typedef float f32x4 __attribute__((ext_vector_type(4)));

// ---------------- K0: convert w to fp16 hi/lo + init counts/worklist -------
__global__ __launch_bounds__(256) void prep(
    const float* __restrict__ w, _Float16* __restrict__ wh,
    _Float16* __restrict__ wlo, float* __restrict__ counts,
    int* __restrict__ wl_count) {
  int gid = blockIdx.x * 256 + threadIdx.x;  // 2048 blocks -> 524288 threads
  float W = w[gid] * 256.f;
  _Float16 h = (_Float16)W;
  wh[gid] = h;
  wlo[gid] = (_Float16)(W - (float)h);
  if (blockIdx.x == 0) {
    counts[threadIdx.x] = 0.f;
    if (threadIdx.x == 0) *wl_count = 0;
  }
}

// ---------------- K1: MFMA gate GEMM, reg-staged prefetch, no split-K ------
constexpr int BM = 64, BN = 128, BK = 64, NT = DDIM / BK;
__global__ __launch_bounds__(256) void gate_gemm_mfma(
    const float* __restrict__ x, const _Float16* __restrict__ wh,
    const _Float16* __restrict__ wlo, float* __restrict__ logits) {
  __shared__ _Float16 Ah[64][72], Al[64][72];    // stride 144B = 9*16B
  __shared__ _Float16 Bh[128][72], Bl[128][72];
  const int tid = threadIdx.x;
  const int bid = blockIdx.x;
  const int mb = bid >> 1, nb = bid & 1;
  const int row0 = mb * BM, col0 = nb * BN;
  const int wave = tid >> 6, lane = tid & 63;
  const int m0 = (wave >> 1) * 32, n0 = (wave & 1) * 64;

  f32x4 acc[2][4];
#pragma unroll
  for (int i = 0; i < 2; i++)
#pragma unroll
    for (int j = 0; j < 4; j++) acc[i][j] = (f32x4){0.f, 0.f, 0.f, 0.f};

  float4 ar[4];
  half8v brh[4], brl[4];

  // load tile t's globals into registers
  auto LOADT = [&](int t) {
    const int k0 = t * BK;
#pragma unroll
    for (int i = 0; i < 4; i++) {
      int f = i * 256 + tid;
      int r = f >> 4, c4 = (f & 15) << 2;
      ar[i] = *reinterpret_cast<const float4*>(
          x + (size_t)(row0 + r) * DDIM + k0 + c4);
    }
#pragma unroll
    for (int i = 0; i < 4; i++) {
      int f = i * 256 + tid;
      int r = f >> 3, k8 = (f & 7) << 3;
      size_t g = (size_t)(col0 + r) * DDIM + k0 + k8;
      brh[i] = *reinterpret_cast<const half8v*>(wh + g);
      brl[i] = *reinterpret_cast<const half8v*>(wlo + g);
    }
  };
  // convert + write regs into LDS
  auto WRITET = [&]() {
#pragma unroll
    for (int i = 0; i < 4; i++) {
      int f = i * 256 + tid;
      int r = f >> 4, c4 = (f & 15) << 2;
      float4 v = ar[i];
      float X0 = v.x * 16.f, X1 = v.y * 16.f, X2 = v.z * 16.f, X3 = v.w * 16.f;
      _Float16 h0 = (_Float16)X0, h1 = (_Float16)X1;
      _Float16 h2 = (_Float16)X2, h3 = (_Float16)X3;
      half4v hv = {h0, h1, h2, h3};
      half4v lv = {(_Float16)(X0 - (float)h0), (_Float16)(X1 - (float)h1),
                   (_Float16)(X2 - (float)h2), (_Float16)(X3 - (float)h3)};
      *reinterpret_cast<half4v*>(&Ah[r][c4]) = hv;
      *reinterpret_cast<half4v*>(&Al[r][c4]) = lv;
    }
#pragma unroll
    for (int i = 0; i < 4; i++) {
      int f = i * 256 + tid;
      int r = f >> 3, k8 = (f & 7) << 3;
      *reinterpret_cast<half8v*>(&Bh[r][k8]) = brh[i];
      *reinterpret_cast<half8v*>(&Bl[r][k8]) = brl[i];
    }
  };

  LOADT(0);
  for (int t = 0; t < NT; t++) {
    WRITET();
    __syncthreads();
    if (t + 1 < NT) LOADT(t + 1);  // in flight during compute
#pragma unroll
    for (int ks = 0; ks < 2; ks++) {
      const int koff = ks * 32 + (lane >> 4) * 8;
      half8v ah[2], al[2], bh[4], bl[4];
#pragma unroll
      for (int mf = 0; mf < 2; mf++) {
        int r = m0 + mf * 16 + (lane & 15);
        ah[mf] = *reinterpret_cast<half8v*>(&Ah[r][koff]);
        al[mf] = *reinterpret_cast<half8v*>(&Al[r][koff]);
      }
#pragma unroll
      for (int nf = 0; nf < 4; nf++) {
        int c = n0 + nf * 16 + (lane & 15);
        bh[nf] = *reinterpret_cast<half8v*>(&Bh[c][koff]);
        bl[nf] = *reinterpret_cast<half8v*>(&Bl[c][koff]);
      }
#pragma unroll
      for (int mf = 0; mf < 2; mf++)
#pragma unroll
        for (int nf = 0; nf < 4; nf++) {
          acc[mf][nf] = __builtin_amdgcn_mfma_f32_16x16x32_f16(
              ah[mf], bh[nf], acc[mf][nf], 0, 0, 0);
          acc[mf][nf] = __builtin_amdgcn_mfma_f32_16x16x32_f16(
              ah[mf], bl[nf], acc[mf][nf], 0, 0, 0);
          acc[mf][nf] = __builtin_amdgcn_mfma_f32_16x16x32_f16(
              al[mf], bh[nf], acc[mf][nf], 0, 0, 0);
        }
    }
    __syncthreads();
  }
  // epilogue: plain stores (deterministic, no atomics)
#pragma unroll
  for (int mf = 0; mf < 2; mf++)
#pragma unroll
    for (int nf = 0; nf < 4; nf++)
#pragma unroll
      for (int r = 0; r < 4; r++) {
        int row = row0 + m0 + mf * 16 + (lane >> 4) * 4 + r;
        int col = col0 + n0 + nf * 16 + (lane & 15);
        logits[(size_t)row * NEXP + col] = acc[mf][nf][r];
      }
}

// ------- K2: fp32 router with margin certification; flag close calls -------
__global__ __launch_bounds__(256) void router_flag(
    const float* __restrict__ logits, const float* __restrict__ bias,
    float* __restrict__ out_scores, float* __restrict__ out_sel,
    float* __restrict__ out_counts, int* __restrict__ wl_count,
    int* __restrict__ wlist) {
  __shared__ int hist[NEXP];
  const int tid = threadIdx.x;
  hist[tid] = 0;
  __syncthreads();

  const int wave = tid >> 6, lane = tid & 63;
  const int t = blockIdx.x * 4 + wave;

  float4 lg = *reinterpret_cast<const float4*>(logits + (size_t)t * NEXP + lane * 4);
  float4 bv = *reinterpret_cast<const float4*>(bias + lane * 4);
  float s[4];
  s[0] = 1.f / (1.f + expf(-lg.x * SCL));
  s[1] = 1.f / (1.f + expf(-lg.y * SCL));
  s[2] = 1.f / (1.f + expf(-lg.z * SCL));
  s[3] = 1.f / (1.f + expf(-lg.w * SCL));
  float c[4] = {s[0] + bv.x, s[1] + bv.y, s[2] + bv.z, s[3] + bv.w};

  float h1 = fmaxf(c[0], c[1]);
  float h2 = fmaxf(c[2], c[3]);
  float m1 = fmaxf(h1, h2);
  float m2 = fmaxf(fminf(h1, h2), fmaxf(fminf(c[0], c[1]), fminf(c[2], c[3])));
#pragma unroll
  for (int d = 1; d <= 4; d <<= 1) {
    float om1 = __shfl_xor(m1, d);
    float om2 = __shfl_xor(m2, d);
    float n1 = fmaxf(m1, om1);
    float n2 = fmaxf(fminf(m1, om1), fmaxf(m2, om2));
    m1 = n1; m2 = n2;
  }
  float gscore = m1 + m2;

  float gs[8];
#pragma unroll
  for (int g = 0; g < 8; g++) gs[g] = __shfl(gscore, g * 8);
  const int gme = lane >> 3;
  int rank = 0;
#pragma unroll
  for (int h = 0; h < 8; h++)
    rank += (gs[h] > gs[gme]) || (gs[h] == gs[gme] && h < gme);
  const bool keep = rank < NLIM;

  float v4 = 0.f, v5 = 0.f;
#pragma unroll
  for (int g = 0; g < 8; g++) {
    int rk = 0;
#pragma unroll
    for (int h = 0; h < 8; h++)
      rk += (gs[h] > gs[g]) || (gs[h] == gs[g] && h < g);
    if (rk == 3) v4 = gs[g];
    if (rk == 4) v5 = gs[g];
  }
  bool flag = (v4 - v5) < 8.f * EPSC;

  float v[4];
#pragma unroll
  for (int j = 0; j < 4; j++) v[j] = keep ? c[j] : -INFINITY;

  float selS[TOPK];
  int selE[TOPK];
  float prevB = 0.f;
#pragma unroll
  for (int kk = 0; kk < TOPK + 1; kk++) {
    float bvv = v[0];
    int bi = lane * 4;
#pragma unroll
    for (int j = 1; j < 4; j++)
      if (v[j] > bvv) { bvv = v[j]; bi = lane * 4 + j; }
#pragma unroll
    for (int d = 1; d <= 32; d <<= 1) {
      float ov = __shfl_xor(bvv, d);
      int oi = __shfl_xor(bi, d);
      if (ov > bvv || (ov == bvv && oi < bi)) { bvv = ov; bi = oi; }
    }
    int ol = bi >> 2, oj = bi & 3;
    if (kk < TOPK) {
      selE[kk] = bi;
      float cand = (oj == 0) ? s[0] : (oj == 1) ? s[1] : (oj == 2) ? s[2] : s[3];
      selS[kk] = __shfl(cand, ol);
    }
    if (kk > 0 && (prevB - bvv) < 2.f * EPSC) flag = true;
    prevB = bvv;
#pragma unroll
    for (int j = 0; j < 4; j++)
      if (lane == ol && j == oj) v[j] = -INFINITY;
  }

  if (!flag) {
    float denom = 1e-20f;
#pragma unroll
    for (int kk = 0; kk < TOPK; kk++) denom += selS[kk];
    float scale = 2.5f / denom;
    if (lane == 0) {
      float4 o;
      o.x = selS[0] * scale; o.y = selS[1] * scale;
      o.z = selS[2] * scale; o.w = selS[3] * scale;
      *reinterpret_cast<float4*>(out_scores + (size_t)t * TOPK) = o;
      o.x = selS[4] * scale; o.y = selS[5] * scale;
      o.z = selS[6] * scale; o.w = selS[7] * scale;
      *reinterpret_cast<float4*>(out_scores + (size_t)t * TOPK + 4) = o;
      float4 e;
      e.x = (float)selE[0]; e.y = (float)selE[1];
      e.z = (float)selE[2]; e.w = (float)selE[3];
      *reinterpret_cast<float4*>(out_sel + (size_t)t * TOPK) = e;
      e.x = (float)selE[4]; e.y = (float)selE[5];
      e.z = (float)selE[6]; e.w = (float)selE[7];
      *reinterpret_cast<float4*>(out_sel + (size_t)t * TOPK + 4) = e;
#pragma unroll
      for (int kk = 0; kk < TOPK; kk++) atomicAdd(&hist[selE[kk]], 1);
    }
  } else if (lane == 0) {
    int i = atomicAdd(wl_count, 1);
    wlist[i] = t;
  }
  __syncthreads();
  int hcount = hist[tid];
  if (hcount) atomicAdd(&out_counts[tid], (float)hcount);
}

// ------- K3: f64 recompute for flagged tokens (coalesced, 4 lanes/expert) --
__global__ __launch_bounds__(256) void fixup_f64(
    const float* __restrict__ x, const float* __restrict__ w,
    const float* __restrict__ bias, float* __restrict__ out_scores,
    float* __restrict__ out_sel, float* __restrict__ out_counts,
    const int* __restrict__ wl_count, const int* __restrict__ wlist) {
  __shared__ float xs[DDIM];   // 8 KB
  __shared__ double sc[NEXP];  // 2 KB
  const int n = *wl_count;
  const int tid = threadIdx.x;
  const int sl = tid & 3, el = tid >> 2;  // 4 lanes per expert, 64 experts/pass

  for (int it = blockIdx.x; it < n; it += gridDim.x) {
    const int t = wlist[it];
#pragma unroll
    for (int i = 0; i < 2; i++)
      reinterpret_cast<float4*>(xs)[i * 256 + tid] =
          reinterpret_cast<const float4*>(x + (size_t)t * DDIM)[i * 256 + tid];
    __syncthreads();

#pragma unroll
    for (int pass = 0; pass < 4; pass++) {
      const int e = pass * 64 + el;
      const float* wr = w + (size_t)e * DDIM;
      double a0 = 0, a1 = 0;
      for (int m = 0; m < DDIM / 16; m++) {
        int k = (m * 4 + sl) * 4;
        float4 wv = *reinterpret_cast<const float4*>(wr + k);
        float4 xv = *reinterpret_cast<const float4*>(xs + k);
        a0 = fma((double)xv.x, (double)wv.x, a0);
        a1 = fma((double)xv.y, (double)wv.y, a1);
        a0 = fma((double)xv.z, (double)wv.z, a0);
        a1 = fma((double)xv.w, (double)wv.w, a1);
      }
      double tot = a0 + a1;
      tot += __shfl_xor(tot, 1);
      tot += __shfl_xor(tot, 2);
      if (sl == 0) sc[e] = 1.0 / (1.0 + exp(-tot));
    }
    __syncthreads();

    if (tid < 64) {
      const int lane = tid;
      double s[4], c[4];
      s[0] = sc[lane * 4 + 0]; s[1] = sc[lane * 4 + 1];
      s[2] = sc[lane * 4 + 2]; s[3] = sc[lane * 4 + 3];
      float4 bv = *reinterpret_cast<const float4*>(bias + lane * 4);
      c[0] = s[0] + (double)bv.x; c[1] = s[1] + (double)bv.y;
      c[2] = s[2] + (double)bv.z; c[3] = s[3] + (double)bv.w;

      double h1 = fmax(c[0], c[1]), l1 = fmin(c[0], c[1]);
      double h2 = fmax(c[2], c[3]), l2 = fmin(c[2], c[3]);
      double m1 = fmax(h1, h2);
      double m2 = fmax(fmin(h1, h2), fmax(l1, l2));
#pragma unroll
      for (int d = 1; d <= 4; d <<= 1) {
        double om1 = __shfl_xor(m1, d);
        double om2 = __shfl_xor(m2, d);
        double n1 = fmax(m1, om1);
        double n2 = fmax(fmin(m1, om1), fmax(m2, om2));
        m1 = n1; m2 = n2;
      }
      double gscore = m1 + m2;
      double gsv[8];
#pragma unroll
      for (int g = 0; g < 8; g++) gsv[g] = __shfl(gscore, g * 8);
      const int gme = lane >> 3;
      int rank = 0;
#pragma unroll
      for (int h = 0; h < 8; h++)
        rank += (gsv[h] > gsv[gme]) || (gsv[h] == gsv[gme] && h < gme);
      const bool keep = rank < NLIM;

      const double NEG = -HUGE_VAL;
      double v[4];
#pragma unroll
      for (int j = 0; j < 4; j++) v[j] = keep ? c[j] : NEG;

      double selS[TOPK];
      int selE[TOPK];
#pragma unroll
      for (int kk = 0; kk < TOPK; kk++) {
        double bvv = v[0];
        int bi = lane * 4;
#pragma unroll
        for (int j = 1; j < 4; j++)
          if (v[j] > bvv) { bvv = v[j]; bi = lane * 4 + j; }
#pragma unroll
        for (int d = 1; d <= 32; d <<= 1) {
          double ov = __shfl_xor(bvv, d);
          int oi = __shfl_xor(bi, d);
          if (ov > bvv || (ov == bvv && oi < bi)) { bvv = ov; bi = oi; }
        }
        selE[kk] = bi;
        int ol = bi >> 2, oj = bi & 3;
        double cand = (oj == 0) ? s[0] : (oj == 1) ? s[1] : (oj == 2) ? s[2] : s[3];
        selS[kk] = __shfl(cand, ol);
#pragma unroll
        for (int j = 0; j < 4; j++)
          if (lane == ol && j == oj) v[j] = NEG;
      }

      double denom = 1e-20;
#pragma unroll
      for (int kk = 0; kk < TOPK; kk++) denom += selS[kk];
      double scale = 2.5 / denom;

      if (lane == 0) {
        float4 o;
        o.x = (float)(selS[0] * scale); o.y = (float)(selS[1] * scale);
        o.z = (float)(selS[2] * scale); o.w = (float)(selS[3] * scale);
        *reinterpret_cast<float4*>(out_scores + (size_t)t * TOPK) = o;
        o.x = (float)(selS[4] * scale); o.y = (float)(selS[5] * scale);
        o.z = (float)(selS[6] * scale); o.w = (float)(selS[7] * scale);
        *reinterpret_cast<float4*>(out_scores + (size_t)t * TOPK + 4) = o;
        float4 e;
        e.x = (float)selE[0]; e.y = (float)selE[1];
        e.z = (float)selE[2]; e.w = (float)selE[3];
        *reinterpret_cast<float4*>(out_sel + (size_t)t * TOPK) = e;
        e.x = (float)selE[4]; e.y = (float)selE[5];
        e.z = (float)selE[6]; e.w = (float)selE[7];
        *reinterpret_cast<float4*>(out_sel + (size_t)t * TOPK + 4) = e;
#pragma unroll
        for (int kk = 0; kk < TOPK; kk++)
          atomicAdd(&out_counts[selE[kk]], 1.0f);
      }
    }
    __syncthreads();
  }
}

extern "C" void kernel_launch(void* const* d_in, const int* in_sizes, int n_in,
                              void* d_out, int out_size, void* d_ws, size_t ws_size,
                              hipStream_t stream) {
  const float* x = (const float*)d_in[0];
  const float* w = (const float*)d_in[1];
  const float* bias = (const float*)d_in[2];
  float* out = (float*)d_out;
  float* out_scores = out;
  float* out_sel = out + T_TOK * TOPK;
  float* out_counts = out + 2 * T_TOK * TOPK;

  char* ws = (char*)d_ws;
  float* logits = (float*)ws;                                   // 16 MB
  _Float16* wh = (_Float16*)(ws + (size_t)16 * 1024 * 1024);    // 1 MB
  _Float16* wlo = (_Float16*)(ws + (size_t)17 * 1024 * 1024);   // 1 MB
  int* wl_count = (int*)(ws + (size_t)18 * 1024 * 1024);
  int* wlist = wl_count + 16;

  prep<<<2048, 256, 0, stream>>>(w, wh, wlo, out_counts, wl_count);
  gate_gemm_mfma<<<512, 256, 0, stream>>>(x, wh, wlo, logits);
  router_flag<<<T_TOK / 4, 256, 0, stream>>>(logits, bias, out_scores,
                                             out_sel, out_counts, wl_count, wlist);
  fixup_f64<<<1024, 256, 0, stream>>>(x, w, bias, out_scores, out_sel,
                                      out_counts, wl_count, wlist);
}

// Round 7
// 226.963 us; speedup vs baseline: 2.3637x; 1.0381x over previous
//
#include <hip/hip_runtime.h>
#include <math.h>

#define T_TOK 16384
#define DDIM 2048
#define NEXP 256
#define TOPK 8
#define NLIM 4

constexpr float EPSC = 1e-5f;         // certified score-space error bound
constexpr float SCL = 1.f / 4096.f;   // undo x*16, w*256 scaling

typedef _Float16 half4v __attribute__((ext_vector_type(4)));
typedef _Float16 half8v __attribute__((ext_vector_type(8)));
typedef float f32x4 __attribute__((ext_vector_type(4)));

// ---------------- K0: convert w to fp16 hi/lo + init counts/worklist -------
__global__ __launch_bounds__(256) void prep(
    const float* __restrict__ w, _Float16* __restrict__ wh,
    _Float16* __restrict__ wlo, float* __restrict__ counts,
    int* __restrict__ wl_count) {
  int gid = blockIdx.x * 256 + threadIdx.x;
  float W = w[gid] * 256.f;
  _Float16 h = (_Float16)W;
  wh[gid] = h;
  wlo[gid] = (_Float16)(W - (float)h);
  if (blockIdx.x == 0) {
    counts[threadIdx.x] = 0.f;
    if (threadIdx.x == 0) *wl_count = 0;
  }
}

// --------- K1: MFMA gate GEMM (fp16 split-2) + sigmoid epilogue ------------
constexpr int BM = 64, BN = 128, BK = 64, NT = DDIM / BK;
__global__ __launch_bounds__(256) void gate_gemm_mfma(
    const float* __restrict__ x, const _Float16* __restrict__ wh,
    const _Float16* __restrict__ wlo, float* __restrict__ scores) {
  __shared__ _Float16 Ah[64][72], Al[64][72];
  __shared__ _Float16 Bh[128][72], Bl[128][72];
  const int tid = threadIdx.x;
  const int bid = blockIdx.x;
  const int mb = bid >> 1, nb = bid & 1;
  const int row0 = mb * BM, col0 = nb * BN;
  const int wave = tid >> 6, lane = tid & 63;
  const int m0 = (wave >> 1) * 32, n0 = (wave & 1) * 64;

  f32x4 acc[2][4];
#pragma unroll
  for (int i = 0; i < 2; i++)
#pragma unroll
    for (int j = 0; j < 4; j++) acc[i][j] = (f32x4){0.f, 0.f, 0.f, 0.f};

  float4 ar[4];
  half8v brh[4], brl[4];

  auto LOADT = [&](int t) {
    const int k0 = t * BK;
#pragma unroll
    for (int i = 0; i < 4; i++) {
      int f = i * 256 + tid;
      int r = f >> 4, c4 = (f & 15) << 2;
      ar[i] = *reinterpret_cast<const float4*>(
          x + (size_t)(row0 + r) * DDIM + k0 + c4);
    }
#pragma unroll
    for (int i = 0; i < 4; i++) {
      int f = i * 256 + tid;
      int r = f >> 3, k8 = (f & 7) << 3;
      size_t g = (size_t)(col0 + r) * DDIM + k0 + k8;
      brh[i] = *reinterpret_cast<const half8v*>(wh + g);
      brl[i] = *reinterpret_cast<const half8v*>(wlo + g);
    }
  };
  auto WRITET = [&]() {
#pragma unroll
    for (int i = 0; i < 4; i++) {
      int f = i * 256 + tid;
      int r = f >> 4, c4 = (f & 15) << 2;
      float4 v = ar[i];
      float X0 = v.x * 16.f, X1 = v.y * 16.f, X2 = v.z * 16.f, X3 = v.w * 16.f;
      _Float16 h0 = (_Float16)X0, h1 = (_Float16)X1;
      _Float16 h2 = (_Float16)X2, h3 = (_Float16)X3;
      half4v hv = {h0, h1, h2, h3};
      half4v lv = {(_Float16)(X0 - (float)h0), (_Float16)(X1 - (float)h1),
                   (_Float16)(X2 - (float)h2), (_Float16)(X3 - (float)h3)};
      *reinterpret_cast<half4v*>(&Ah[r][c4]) = hv;
      *reinterpret_cast<half4v*>(&Al[r][c4]) = lv;
    }
#pragma unroll
    for (int i = 0; i < 4; i++) {
      int f = i * 256 + tid;
      int r = f >> 3, k8 = (f & 7) << 3;
      *reinterpret_cast<half8v*>(&Bh[r][k8]) = brh[i];
      *reinterpret_cast<half8v*>(&Bl[r][k8]) = brl[i];
    }
  };

  LOADT(0);
  for (int t = 0; t < NT; t++) {
    WRITET();
    __syncthreads();
    if (t + 1 < NT) LOADT(t + 1);
#pragma unroll
    for (int ks = 0; ks < 2; ks++) {
      const int koff = ks * 32 + (lane >> 4) * 8;
      half8v ah[2], al[2], bh[4], bl[4];
#pragma unroll
      for (int mf = 0; mf < 2; mf++) {
        int r = m0 + mf * 16 + (lane & 15);
        ah[mf] = *reinterpret_cast<half8v*>(&Ah[r][koff]);
        al[mf] = *reinterpret_cast<half8v*>(&Al[r][koff]);
      }
#pragma unroll
      for (int nf = 0; nf < 4; nf++) {
        int c = n0 + nf * 16 + (lane & 15);
        bh[nf] = *reinterpret_cast<half8v*>(&Bh[c][koff]);
        bl[nf] = *reinterpret_cast<half8v*>(&Bl[c][koff]);
      }
#pragma unroll
      for (int mf = 0; mf < 2; mf++)
#pragma unroll
        for (int nf = 0; nf < 4; nf++) {
          acc[mf][nf] = __builtin_amdgcn_mfma_f32_16x16x32_f16(
              ah[mf], bh[nf], acc[mf][nf], 0, 0, 0);
          acc[mf][nf] = __builtin_amdgcn_mfma_f32_16x16x32_f16(
              ah[mf], bl[nf], acc[mf][nf], 0, 0, 0);
          acc[mf][nf] = __builtin_amdgcn_mfma_f32_16x16x32_f16(
              al[mf], bh[nf], acc[mf][nf], 0, 0, 0);
        }
    }
    __syncthreads();
  }
  // epilogue: sigmoid, plain stores
#pragma unroll
  for (int mf = 0; mf < 2; mf++)
#pragma unroll
    for (int nf = 0; nf < 4; nf++)
#pragma unroll
      for (int r = 0; r < 4; r++) {
        int row = row0 + m0 + mf * 16 + (lane >> 4) * 4 + r;
        int col = col0 + n0 + nf * 16 + (lane & 15);
        float sv = 1.f / (1.f + expf(-acc[mf][nf][r] * SCL));
        scores[(size_t)row * NEXP + col] = sv;
      }
}

// -------- K2: serial-lane router: one lane per token, u64-key top-9 --------
__global__ __launch_bounds__(64) void router_serial(
    const float* __restrict__ scores, const float* __restrict__ bias,
    float* __restrict__ out_scores, float* __restrict__ out_sel,
    float* __restrict__ out_counts, int* __restrict__ wl_count,
    int* __restrict__ wlist) {
  __shared__ float S[64][257];  // biased scores; stride 257 -> 2-way banks
  __shared__ float BS[256];
  __shared__ int hist[256];
  const int lane = threadIdx.x;
  const int t0 = blockIdx.x * 64;

#pragma unroll
  for (int i = 0; i < 4; i++) {
    hist[i * 64 + lane] = 0;
    BS[i * 64 + lane] = bias[i * 64 + lane];
  }
  float4 bv = *reinterpret_cast<const float4*>(bias + lane * 4);
  for (int r = 0; r < 64; r++) {
    float4 v = *reinterpret_cast<const float4*>(
        scores + (size_t)(t0 + r) * NEXP + lane * 4);
    S[r][lane * 4 + 0] = v.x + bv.x;
    S[r][lane * 4 + 1] = v.y + bv.y;
    S[r][lane * 4 + 2] = v.z + bv.z;
    S[r][lane * 4 + 3] = v.w + bv.w;
  }
  __syncthreads();

  const float* Srow = S[lane];
  const int t = t0 + lane;

  // phase A: per-group top-2 sums
  float gsArr[8];
#pragma unroll
  for (int g = 0; g < 8; g++) {
    float m1 = -INFINITY, m2 = -INFINITY;
#pragma unroll 4
    for (int k = 0; k < 32; k++) {
      float c = Srow[g * 32 + k];
      float mx = fmaxf(m1, c);
      m2 = fmaxf(m2, fminf(m1, c));
      m1 = mx;
    }
    gsArr[g] = m1 + m2;
  }

  // group ranks -> kept nibble-pack, 4th/5th margin
  int kgpack = 0;
  float v4 = 0.f, v5 = 0.f;
#pragma unroll
  for (int g = 7; g >= 0; g--) {
    int rk = 0;
#pragma unroll
    for (int h = 0; h < 8; h++)
      rk += (gsArr[h] > gsArr[g]) || (gsArr[h] == gsArr[g] && h < g);
    if (rk < NLIM) kgpack = (kgpack << 4) | g;
    if (rk == 3) v4 = gsArr[g];
    if (rk == 4) v5 = gsArr[g];
  }
  bool flag = (v4 - v5) < 8.f * EPSC;

  // phase B: branchless 9-slot insertion over 128 eligible, u64 keys
  unsigned long long L[9];
#pragma unroll
  for (int i = 0; i < 9; i++) L[i] = 0ULL;
#pragma unroll
  for (int gi = 0; gi < 4; gi++) {
    const int cb = ((kgpack >> (gi * 4)) & 15) * 32;
#pragma unroll 2
    for (int k = 0; k < 32; k++) {
      float c = Srow[cb + k];
      unsigned int bits = __float_as_uint(c + 1.0f);
      unsigned long long key =
          ((unsigned long long)bits << 8) | (unsigned)(255 - (cb + k));
#pragma unroll
      for (int sl = 0; sl < 9; sl++) {
        bool gt = key > L[sl];
        unsigned long long nl = gt ? key : L[sl];
        key = gt ? L[sl] : key;
        L[sl] = nl;
      }
    }
  }

  int selE[9];
  float cval[9];
#pragma unroll
  for (int i = 0; i < 9; i++) {
    selE[i] = 255 - (int)(L[i] & 0xFFULL);
    cval[i] = __uint_as_float((unsigned)(L[i] >> 8)) - 1.0f;
  }
#pragma unroll
  for (int i = 0; i < 8; i++)
    flag = flag || ((cval[i] - cval[i + 1]) < 2.f * EPSC);

  if (!flag) {
    float s[8];
    float denom = 1e-20f;
#pragma unroll
    for (int i = 0; i < 8; i++) {
      s[i] = Srow[selE[i]] - BS[selE[i]];
      denom += s[i];
    }
    float scale = 2.5f / denom;
    float4 o0 = {s[0] * scale, s[1] * scale, s[2] * scale, s[3] * scale};
    float4 o1 = {s[4] * scale, s[5] * scale, s[6] * scale, s[7] * scale};
    *reinterpret_cast<float4*>(out_scores + (size_t)t * TOPK) = o0;
    *reinterpret_cast<float4*>(out_scores + (size_t)t * TOPK + 4) = o1;
    float4 e0 = {(float)selE[0], (float)selE[1], (float)selE[2], (float)selE[3]};
    float4 e1 = {(float)selE[4], (float)selE[5], (float)selE[6], (float)selE[7]};
    *reinterpret_cast<float4*>(out_sel + (size_t)t * TOPK) = e0;
    *reinterpret_cast<float4*>(out_sel + (size_t)t * TOPK + 4) = e1;
#pragma unroll
    for (int i = 0; i < 8; i++) atomicAdd(&hist[selE[i]], 1);
  } else {
    int i = atomicAdd(wl_count, 1);
    wlist[i] = t;
  }
  __syncthreads();
#pragma unroll
  for (int i = 0; i < 4; i++) {
    int h = hist[i * 64 + lane];
    if (h) atomicAdd(&out_counts[i * 64 + lane], (float)h);
  }
}

// ------- K3: f64 recompute, 4 tokens/block (w reuse), 4-wave selection -----
__global__ __launch_bounds__(256) void fixup_f64(
    const float* __restrict__ x, const float* __restrict__ w,
    const float* __restrict__ bias, float* __restrict__ out_scores,
    float* __restrict__ out_sel, float* __restrict__ out_counts,
    const int* __restrict__ wl_count, const int* __restrict__ wlist) {
  __shared__ float xs[4][DDIM];   // 32 KB
  __shared__ double sc[4][NEXP];  // 8 KB
  __shared__ int toks[4];
  const int n = *wl_count;
  const int tid = threadIdx.x;
  const int sl = tid & 3, el = tid >> 2;

  for (int base = blockIdx.x * 4; base < n; base += gridDim.x * 4) {
    const int nt = min(4, n - base);
    __syncthreads();  // protect xs/sc/toks from previous iteration readers
    if (tid < 4) toks[tid] = wlist[base + ((tid < nt) ? tid : 0)];
    __syncthreads();
    for (int i = tid; i < nt * 512; i += 256) {
      int tk = i >> 9, off = i & 511;
      reinterpret_cast<float4*>(xs[tk])[off] =
          reinterpret_cast<const float4*>(x + (size_t)toks[tk] * DDIM)[off];
    }
    __syncthreads();

#pragma unroll 1
    for (int pass = 0; pass < 4; pass++) {
      const int e = pass * 64 + el;
      const float* wr = w + (size_t)e * DDIM;
      double a00 = 0, a01 = 0, a10 = 0, a11 = 0;
      double a20 = 0, a21 = 0, a30 = 0, a31 = 0;
      for (int m = 0; m < DDIM / 16; m++) {
        const int k = (m * 4 + sl) * 4;
        float4 wv = *reinterpret_cast<const float4*>(wr + k);
        float4 x0 = *reinterpret_cast<const float4*>(&xs[0][k]);
        float4 x1 = *reinterpret_cast<const float4*>(&xs[1][k]);
        float4 x2 = *reinterpret_cast<const float4*>(&xs[2][k]);
        float4 x3 = *reinterpret_cast<const float4*>(&xs[3][k]);
        a00 = fma((double)x0.x, (double)wv.x, a00);
        a01 = fma((double)x0.y, (double)wv.y, a01);
        a00 = fma((double)x0.z, (double)wv.z, a00);
        a01 = fma((double)x0.w, (double)wv.w, a01);
        a10 = fma((double)x1.x, (double)wv.x, a10);
        a11 = fma((double)x1.y, (double)wv.y, a11);
        a10 = fma((double)x1.z, (double)wv.z, a10);
        a11 = fma((double)x1.w, (double)wv.w, a11);
        a20 = fma((double)x2.x, (double)wv.x, a20);
        a21 = fma((double)x2.y, (double)wv.y, a21);
        a20 = fma((double)x2.z, (double)wv.z, a20);
        a21 = fma((double)x2.w, (double)wv.w, a21);
        a30 = fma((double)x3.x, (double)wv.x, a30);
        a31 = fma((double)x3.y, (double)wv.y, a31);
        a30 = fma((double)x3.z, (double)wv.z, a30);
        a31 = fma((double)x3.w, (double)wv.w, a31);
      }
      double r0 = a00 + a01, r1 = a10 + a11, r2 = a20 + a21, r3 = a30 + a31;
      r0 += __shfl_xor(r0, 1); r0 += __shfl_xor(r0, 2);
      r1 += __shfl_xor(r1, 1); r1 += __shfl_xor(r1, 2);
      r2 += __shfl_xor(r2, 1); r2 += __shfl_xor(r2, 2);
      r3 += __shfl_xor(r3, 1); r3 += __shfl_xor(r3, 2);
      if (sl == 0) {
        sc[0][e] = 1.0 / (1.0 + exp(-r0));
        sc[1][e] = 1.0 / (1.0 + exp(-r1));
        sc[2][e] = 1.0 / (1.0 + exp(-r2));
        sc[3][e] = 1.0 / (1.0 + exp(-r3));
      }
    }
    __syncthreads();

    const int wv = tid >> 6, lane = tid & 63;
    if (wv < nt) {
      const int t = toks[wv];
      double s[4], c[4];
      s[0] = sc[wv][lane * 4 + 0]; s[1] = sc[wv][lane * 4 + 1];
      s[2] = sc[wv][lane * 4 + 2]; s[3] = sc[wv][lane * 4 + 3];
      float4 bvv = *reinterpret_cast<const float4*>(bias + lane * 4);
      c[0] = s[0] + (double)bvv.x; c[1] = s[1] + (double)bvv.y;
      c[2] = s[2] + (double)bvv.z; c[3] = s[3] + (double)bvv.w;

      double h1 = fmax(c[0], c[1]), l1 = fmin(c[0], c[1]);
      double h2 = fmax(c[2], c[3]), l2 = fmin(c[2], c[3]);
      double m1 = fmax(h1, h2);
      double m2 = fmax(fmin(h1, h2), fmax(l1, l2));
#pragma unroll
      for (int d = 1; d <= 4; d <<= 1) {
        double om1 = __shfl_xor(m1, d);
        double om2 = __shfl_xor(m2, d);
        double n1 = fmax(m1, om1);
        double n2 = fmax(fmin(m1, om1), fmax(m2, om2));
        m1 = n1; m2 = n2;
      }
      double gscore = m1 + m2;
      double gsv[8];
#pragma unroll
      for (int g = 0; g < 8; g++) gsv[g] = __shfl(gscore, g * 8);
      const int gme = lane >> 3;
      int rank = 0;
#pragma unroll
      for (int h = 0; h < 8; h++)
        rank += (gsv[h] > gsv[gme]) || (gsv[h] == gsv[gme] && h < gme);
      const bool keep = rank < NLIM;

      const double NEG = -HUGE_VAL;
      double v[4];
#pragma unroll
      for (int j = 0; j < 4; j++) v[j] = keep ? c[j] : NEG;

      double selS[TOPK];
      int selE[TOPK];
#pragma unroll
      for (int kk = 0; kk < TOPK; kk++) {
        double bvv2 = v[0];
        int bi = lane * 4;
#pragma unroll
        for (int j = 1; j < 4; j++)
          if (v[j] > bvv2) { bvv2 = v[j]; bi = lane * 4 + j; }
#pragma unroll
        for (int d = 1; d <= 32; d <<= 1) {
          double ov = __shfl_xor(bvv2, d);
          int oi = __shfl_xor(bi, d);
          if (ov > bvv2 || (ov == bvv2 && oi < bi)) { bvv2 = ov; bi = oi; }
        }
        selE[kk] = bi;
        int ol = bi >> 2, oj = bi & 3;
        double cand = (oj == 0) ? s[0] : (oj == 1) ? s[1] : (oj == 2) ? s[2] : s[3];
        selS[kk] = __shfl(cand, ol);
#pragma unroll
        for (int j = 0; j < 4; j++)
          if (lane == ol && j == oj) v[j] = NEG;
      }

      double denom = 1e-20;
#pragma unroll
      for (int kk = 0; kk < TOPK; kk++) denom += selS[kk];
      double scale = 2.5 / denom;

      if (lane == 0) {
        float4 o;
        o.x = (float)(selS[0] * scale); o.y = (float)(selS[1] * scale);
        o.z = (float)(selS[2] * scale); o.w = (float)(selS[3] * scale);
        *reinterpret_cast<float4*>(out_scores + (size_t)t * TOPK) = o;
        o.x = (float)(selS[4] * scale); o.y = (float)(selS[5] * scale);
        o.z = (float)(selS[6] * scale); o.w = (float)(selS[7] * scale);
        *reinterpret_cast<float4*>(out_scores + (size_t)t * TOPK + 4) = o;
        float4 e;
        e.x = (float)selE[0]; e.y = (float)selE[1];
        e.z = (float)selE[2]; e.w = (float)selE[3];
        *reinterpret_cast<float4*>(out_sel + (size_t)t * TOPK) = e;
        e.x = (float)selE[4]; e.y = (float)selE[5];
        e.z = (float)selE[6]; e.w = (float)selE[7];
        *reinterpret_cast<float4*>(out_sel + (size_t)t * TOPK + 4) = e;
#pragma unroll
        for (int kk = 0; kk < TOPK; kk++)
          atomicAdd(&out_counts[selE[kk]], 1.0f);
      }
    }
    __syncthreads();
  }
}

extern "C" void kernel_launch(void* const* d_in, const int* in_sizes, int n_in,
                              void* d_out, int out_size, void* d_ws, size_t ws_size,
                              hipStream_t stream) {
  const float* x = (const float*)d_in[0];
  const float* w = (const float*)d_in[1];
  const float* bias = (const float*)d_in[2];
  float* out = (float*)d_out;
  float* out_scores = out;
  float* out_sel = out + T_TOK * TOPK;
  float* out_counts = out + 2 * T_TOK * TOPK;

  char* ws = (char*)d_ws;
  float* scores = (float*)ws;                                   // 16 MB
  _Float16* wh = (_Float16*)(ws + (size_t)16 * 1024 * 1024);    // 1 MB
  _Float16* wlo = (_Float16*)(ws + (size_t)17 * 1024 * 1024);   // 1 MB
  int* wl_count = (int*)(ws + (size_t)18 * 1024 * 1024);
  int* wlist = wl_count + 16;

  prep<<<2048, 256, 0, stream>>>(w, wh, wlo, out_counts, wl_count);
  gate_gemm_mfma<<<512, 256, 0, stream>>>(x, wh, wlo, scores);
  router_serial<<<T_TOK / 64, 64, 0, stream>>>(scores, bias, out_scores,
                                               out_sel, out_counts, wl_count,
                                               wlist);
  fixup_f64<<<512, 256, 0, stream>>>(x, w, bias, out_scores, out_sel,
                                     out_counts, wl_count, wlist);
}

// Round 8
// 209.452 us; speedup vs baseline: 2.5613x; 1.0836x over previous
//
#include <hip/hip_runtime.h>
#include <math.h>

#define T_TOK 16384
#define DDIM 2048
#define NEXP 256
#define TOPK 8
#define NLIM 4

constexpr float EPSC = 1e-5f;         // certified score-space error bound
constexpr float SCL = 1.f / 4096.f;   // undo x*16, w*256 scaling

typedef _Float16 half4v __attribute__((ext_vector_type(4)));
typedef _Float16 half8v __attribute__((ext_vector_type(8)));
typedef float f32x4 __attribute__((ext_vector_type(4)));

// ---------------- K0: convert w to fp16 hi/lo + init counts/worklist -------
__global__ __launch_bounds__(256) void prep(
    const float* __restrict__ w, _Float16* __restrict__ wh,
    _Float16* __restrict__ wlo, float* __restrict__ counts,
    int* __restrict__ wl_count) {
  int gid = blockIdx.x * 256 + threadIdx.x;
  float W = w[gid] * 256.f;
  _Float16 h = (_Float16)W;
  wh[gid] = h;
  wlo[gid] = (_Float16)(W - (float)h);
  if (blockIdx.x == 0) {
    counts[threadIdx.x] = 0.f;
    if (threadIdx.x == 0) *wl_count = 0;
  }
}

// --------- K1: MFMA gate GEMM (fp16 split-2) + sigmoid epilogue ------------
constexpr int BM = 64, BN = 128, BK = 64, NT = DDIM / BK;
__global__ __launch_bounds__(256) void gate_gemm_mfma(
    const float* __restrict__ x, const _Float16* __restrict__ wh,
    const _Float16* __restrict__ wlo, float* __restrict__ scores) {
  __shared__ _Float16 Ah[64][72], Al[64][72];
  __shared__ _Float16 Bh[128][72], Bl[128][72];
  const int tid = threadIdx.x;
  const int bid = blockIdx.x;
  const int mb = bid >> 1, nb = bid & 1;
  const int row0 = mb * BM, col0 = nb * BN;
  const int wave = tid >> 6, lane = tid & 63;
  const int m0 = (wave >> 1) * 32, n0 = (wave & 1) * 64;

  f32x4 acc[2][4];
#pragma unroll
  for (int i = 0; i < 2; i++)
#pragma unroll
    for (int j = 0; j < 4; j++) acc[i][j] = (f32x4){0.f, 0.f, 0.f, 0.f};

  float4 ar[4];
  half8v brh[4], brl[4];

  auto LOADT = [&](int t) {
    const int k0 = t * BK;
#pragma unroll
    for (int i = 0; i < 4; i++) {
      int f = i * 256 + tid;
      int r = f >> 4, c4 = (f & 15) << 2;
      ar[i] = *reinterpret_cast<const float4*>(
          x + (size_t)(row0 + r) * DDIM + k0 + c4);
    }
#pragma unroll
    for (int i = 0; i < 4; i++) {
      int f = i * 256 + tid;
      int r = f >> 3, k8 = (f & 7) << 3;
      size_t g = (size_t)(col0 + r) * DDIM + k0 + k8;
      brh[i] = *reinterpret_cast<const half8v*>(wh + g);
      brl[i] = *reinterpret_cast<const half8v*>(wlo + g);
    }
  };
  auto WRITET = [&]() {
#pragma unroll
    for (int i = 0; i < 4; i++) {
      int f = i * 256 + tid;
      int r = f >> 4, c4 = (f & 15) << 2;
      float4 v = ar[i];
      float X0 = v.x * 16.f, X1 = v.y * 16.f, X2 = v.z * 16.f, X3 = v.w * 16.f;
      _Float16 h0 = (_Float16)X0, h1 = (_Float16)X1;
      _Float16 h2 = (_Float16)X2, h3 = (_Float16)X3;
      half4v hv = {h0, h1, h2, h3};
      half4v lv = {(_Float16)(X0 - (float)h0), (_Float16)(X1 - (float)h1),
                   (_Float16)(X2 - (float)h2), (_Float16)(X3 - (float)h3)};
      *reinterpret_cast<half4v*>(&Ah[r][c4]) = hv;
      *reinterpret_cast<half4v*>(&Al[r][c4]) = lv;
    }
#pragma unroll
    for (int i = 0; i < 4; i++) {
      int f = i * 256 + tid;
      int r = f >> 3, k8 = (f & 7) << 3;
      *reinterpret_cast<half8v*>(&Bh[r][k8]) = brh[i];
      *reinterpret_cast<half8v*>(&Bl[r][k8]) = brl[i];
    }
  };

  LOADT(0);
  for (int t = 0; t < NT; t++) {
    WRITET();
    __syncthreads();
    if (t + 1 < NT) LOADT(t + 1);
#pragma unroll
    for (int ks = 0; ks < 2; ks++) {
      const int koff = ks * 32 + (lane >> 4) * 8;
      half8v ah[2], al[2], bh[4], bl[4];
#pragma unroll
      for (int mf = 0; mf < 2; mf++) {
        int r = m0 + mf * 16 + (lane & 15);
        ah[mf] = *reinterpret_cast<half8v*>(&Ah[r][koff]);
        al[mf] = *reinterpret_cast<half8v*>(&Al[r][koff]);
      }
#pragma unroll
      for (int nf = 0; nf < 4; nf++) {
        int c = n0 + nf * 16 + (lane & 15);
        bh[nf] = *reinterpret_cast<half8v*>(&Bh[c][koff]);
        bl[nf] = *reinterpret_cast<half8v*>(&Bl[c][koff]);
      }
#pragma unroll
      for (int mf = 0; mf < 2; mf++)
#pragma unroll
        for (int nf = 0; nf < 4; nf++) {
          acc[mf][nf] = __builtin_amdgcn_mfma_f32_16x16x32_f16(
              ah[mf], bh[nf], acc[mf][nf], 0, 0, 0);
          acc[mf][nf] = __builtin_amdgcn_mfma_f32_16x16x32_f16(
              ah[mf], bl[nf], acc[mf][nf], 0, 0, 0);
          acc[mf][nf] = __builtin_amdgcn_mfma_f32_16x16x32_f16(
              al[mf], bh[nf], acc[mf][nf], 0, 0, 0);
        }
    }
    __syncthreads();
  }
  // epilogue: sigmoid, plain stores
#pragma unroll
  for (int mf = 0; mf < 2; mf++)
#pragma unroll
    for (int nf = 0; nf < 4; nf++)
#pragma unroll
      for (int r = 0; r < 4; r++) {
        int row = row0 + m0 + mf * 16 + (lane >> 4) * 4 + r;
        int col = col0 + n0 + nf * 16 + (lane & 15);
        float sv = 1.f / (1.f + expf(-acc[mf][nf][r] * SCL));
        scores[(size_t)row * NEXP + col] = sv;
      }
}

// -------- K2: serial-lane router: one lane per token, u64-key top-9 --------
__global__ __launch_bounds__(64) void router_serial(
    const float* __restrict__ scores, const float* __restrict__ bias,
    float* __restrict__ out_scores, float* __restrict__ out_sel,
    float* __restrict__ out_counts, int* __restrict__ wl_count,
    int* __restrict__ wlist) {
  __shared__ float S[64][257];  // biased scores; stride 257 -> 2-way banks
  __shared__ float BS[256];
  __shared__ int hist[256];
  const int lane = threadIdx.x;
  const int t0 = blockIdx.x * 64;

#pragma unroll
  for (int i = 0; i < 4; i++) {
    hist[i * 64 + lane] = 0;
    BS[i * 64 + lane] = bias[i * 64 + lane];
  }
  float4 bv = *reinterpret_cast<const float4*>(bias + lane * 4);
  for (int r = 0; r < 64; r++) {
    float4 v = *reinterpret_cast<const float4*>(
        scores + (size_t)(t0 + r) * NEXP + lane * 4);
    S[r][lane * 4 + 0] = v.x + bv.x;
    S[r][lane * 4 + 1] = v.y + bv.y;
    S[r][lane * 4 + 2] = v.z + bv.z;
    S[r][lane * 4 + 3] = v.w + bv.w;
  }
  __syncthreads();

  const float* Srow = S[lane];
  const int t = t0 + lane;

  // phase A: per-group top-2 sums
  float gsArr[8];
#pragma unroll
  for (int g = 0; g < 8; g++) {
    float m1 = -INFINITY, m2 = -INFINITY;
#pragma unroll 4
    for (int k = 0; k < 32; k++) {
      float c = Srow[g * 32 + k];
      float mx = fmaxf(m1, c);
      m2 = fmaxf(m2, fminf(m1, c));
      m1 = mx;
    }
    gsArr[g] = m1 + m2;
  }

  // group ranks -> kept nibble-pack, 4th/5th margin
  int kgpack = 0;
  float v4 = 0.f, v5 = 0.f;
#pragma unroll
  for (int g = 7; g >= 0; g--) {
    int rk = 0;
#pragma unroll
    for (int h = 0; h < 8; h++)
      rk += (gsArr[h] > gsArr[g]) || (gsArr[h] == gsArr[g] && h < g);
    if (rk < NLIM) kgpack = (kgpack << 4) | g;
    if (rk == 3) v4 = gsArr[g];
    if (rk == 4) v5 = gsArr[g];
  }
  bool flag = (v4 - v5) < 8.f * EPSC;

  // phase B: branchless 9-slot insertion over 128 eligible, u64 keys
  unsigned long long L[9];
#pragma unroll
  for (int i = 0; i < 9; i++) L[i] = 0ULL;
#pragma unroll
  for (int gi = 0; gi < 4; gi++) {
    const int cb = ((kgpack >> (gi * 4)) & 15) * 32;
#pragma unroll 2
    for (int k = 0; k < 32; k++) {
      float c = Srow[cb + k];
      unsigned int bits = __float_as_uint(c + 1.0f);
      unsigned long long key =
          ((unsigned long long)bits << 8) | (unsigned)(255 - (cb + k));
#pragma unroll
      for (int sl = 0; sl < 9; sl++) {
        bool gt = key > L[sl];
        unsigned long long nl = gt ? key : L[sl];
        key = gt ? L[sl] : key;
        L[sl] = nl;
      }
    }
  }

  int selE[9];
  float cval[9];
#pragma unroll
  for (int i = 0; i < 9; i++) {
    selE[i] = 255 - (int)(L[i] & 0xFFULL);
    cval[i] = __uint_as_float((unsigned)(L[i] >> 8)) - 1.0f;
  }
#pragma unroll
  for (int i = 0; i < 8; i++)
    flag = flag || ((cval[i] - cval[i + 1]) < 2.f * EPSC);

  if (!flag) {
    float s[8];
    float denom = 1e-20f;
#pragma unroll
    for (int i = 0; i < 8; i++) {
      s[i] = Srow[selE[i]] - BS[selE[i]];
      denom += s[i];
    }
    float scale = 2.5f / denom;
    float4 o0 = {s[0] * scale, s[1] * scale, s[2] * scale, s[3] * scale};
    float4 o1 = {s[4] * scale, s[5] * scale, s[6] * scale, s[7] * scale};
    *reinterpret_cast<float4*>(out_scores + (size_t)t * TOPK) = o0;
    *reinterpret_cast<float4*>(out_scores + (size_t)t * TOPK + 4) = o1;
    float4 e0 = {(float)selE[0], (float)selE[1], (float)selE[2], (float)selE[3]};
    float4 e1 = {(float)selE[4], (float)selE[5], (float)selE[6], (float)selE[7]};
    *reinterpret_cast<float4*>(out_sel + (size_t)t * TOPK) = e0;
    *reinterpret_cast<float4*>(out_sel + (size_t)t * TOPK + 4) = e1;
#pragma unroll
    for (int i = 0; i < 8; i++) atomicAdd(&hist[selE[i]], 1);
  } else {
    int i = atomicAdd(wl_count, 1);
    wlist[i] = t;
  }
  __syncthreads();
#pragma unroll
  for (int i = 0; i < 4; i++) {
    int h = hist[i * 64 + lane];
    if (h) atomicAdd(&out_counts[i * 64 + lane], (float)h);
  }
}

// --- K3: f64 fixup, 1 token/block, coalesced full-wave expert-row dots -----
__global__ __launch_bounds__(256) void fixup_f64(
    const float* __restrict__ x, const float* __restrict__ w,
    const float* __restrict__ bias, float* __restrict__ out_scores,
    float* __restrict__ out_sel, float* __restrict__ out_counts,
    const int* __restrict__ wl_count, const int* __restrict__ wlist) {
  __shared__ double sc[NEXP];
  const int n = *wl_count;
  const int tid = threadIdx.x;
  const int wv = tid >> 6, lane = tid & 63;

  for (int it = blockIdx.x; it < n; it += gridDim.x) {
    const int t = wlist[it];
    // each lane holds x[t][p*512 + lane*8 .. +7] for p=0..3 (full row in wave)
    const float* xrow = x + (size_t)t * DDIM + lane * 8;
    float4 xr[4][2];
#pragma unroll
    for (int p = 0; p < 4; p++) {
      xr[p][0] = *reinterpret_cast<const float4*>(xrow + p * 512);
      xr[p][1] = *reinterpret_cast<const float4*>(xrow + p * 512 + 4);
    }

    double myLogit = 0.0;
    // wave wv owns experts wv*64..wv*64+63; one expert per iteration,
    // whole wave reads that expert's row coalesced (64 lanes x 16B)
#pragma unroll 2
    for (int e = 0; e < 64; e++) {
      const float* wr = w + (size_t)(wv * 64 + e) * DDIM + lane * 8;
      double a0 = 0, a1 = 0;
#pragma unroll
      for (int p = 0; p < 4; p++) {
        float4 w0 = *reinterpret_cast<const float4*>(wr + p * 512);
        float4 w1 = *reinterpret_cast<const float4*>(wr + p * 512 + 4);
        a0 = fma((double)xr[p][0].x, (double)w0.x, a0);
        a1 = fma((double)xr[p][0].y, (double)w0.y, a1);
        a0 = fma((double)xr[p][0].z, (double)w0.z, a0);
        a1 = fma((double)xr[p][0].w, (double)w0.w, a1);
        a0 = fma((double)xr[p][1].x, (double)w1.x, a0);
        a1 = fma((double)xr[p][1].y, (double)w1.y, a1);
        a0 = fma((double)xr[p][1].z, (double)w1.z, a0);
        a1 = fma((double)xr[p][1].w, (double)w1.w, a1);
      }
      double tot = a0 + a1;
#pragma unroll
      for (int d = 1; d <= 32; d <<= 1) tot += __shfl_xor(tot, d);
      if (lane == e) myLogit = tot;
    }
    sc[wv * 64 + lane] = 1.0 / (1.0 + exp(-myLogit));
    __syncthreads();

    if (tid < 64) {
      double s[4], c[4];
      s[0] = sc[lane * 4 + 0]; s[1] = sc[lane * 4 + 1];
      s[2] = sc[lane * 4 + 2]; s[3] = sc[lane * 4 + 3];
      float4 bvv = *reinterpret_cast<const float4*>(bias + lane * 4);
      c[0] = s[0] + (double)bvv.x; c[1] = s[1] + (double)bvv.y;
      c[2] = s[2] + (double)bvv.z; c[3] = s[3] + (double)bvv.w;

      double h1 = fmax(c[0], c[1]), l1 = fmin(c[0], c[1]);
      double h2 = fmax(c[2], c[3]), l2 = fmin(c[2], c[3]);
      double m1 = fmax(h1, h2);
      double m2 = fmax(fmin(h1, h2), fmax(l1, l2));
#pragma unroll
      for (int d = 1; d <= 4; d <<= 1) {
        double om1 = __shfl_xor(m1, d);
        double om2 = __shfl_xor(m2, d);
        double n1 = fmax(m1, om1);
        double n2 = fmax(fmin(m1, om1), fmax(m2, om2));
        m1 = n1; m2 = n2;
      }
      double gscore = m1 + m2;
      double gsv[8];
#pragma unroll
      for (int g = 0; g < 8; g++) gsv[g] = __shfl(gscore, g * 8);
      const int gme = lane >> 3;
      int rank = 0;
#pragma unroll
      for (int h = 0; h < 8; h++)
        rank += (gsv[h] > gsv[gme]) || (gsv[h] == gsv[gme] && h < gme);
      const bool keep = rank < NLIM;

      const double NEG = -HUGE_VAL;
      double v[4];
#pragma unroll
      for (int j = 0; j < 4; j++) v[j] = keep ? c[j] : NEG;

      double selS[TOPK];
      int selE[TOPK];
#pragma unroll
      for (int kk = 0; kk < TOPK; kk++) {
        double bvv2 = v[0];
        int bi = lane * 4;
#pragma unroll
        for (int j = 1; j < 4; j++)
          if (v[j] > bvv2) { bvv2 = v[j]; bi = lane * 4 + j; }
#pragma unroll
        for (int d = 1; d <= 32; d <<= 1) {
          double ov = __shfl_xor(bvv2, d);
          int oi = __shfl_xor(bi, d);
          if (ov > bvv2 || (ov == bvv2 && oi < bi)) { bvv2 = ov; bi = oi; }
        }
        selE[kk] = bi;
        int ol = bi >> 2, oj = bi & 3;
        double cand = (oj == 0) ? s[0] : (oj == 1) ? s[1] : (oj == 2) ? s[2] : s[3];
        selS[kk] = __shfl(cand, ol);
#pragma unroll
        for (int j = 0; j < 4; j++)
          if (lane == ol && j == oj) v[j] = NEG;
      }

      double denom = 1e-20;
#pragma unroll
      for (int kk = 0; kk < TOPK; kk++) denom += selS[kk];
      double scale = 2.5 / denom;

      if (lane == 0) {
        float4 o;
        o.x = (float)(selS[0] * scale); o.y = (float)(selS[1] * scale);
        o.z = (float)(selS[2] * scale); o.w = (float)(selS[3] * scale);
        *reinterpret_cast<float4*>(out_scores + (size_t)t * TOPK) = o;
        o.x = (float)(selS[4] * scale); o.y = (float)(selS[5] * scale);
        o.z = (float)(selS[6] * scale); o.w = (float)(selS[7] * scale);
        *reinterpret_cast<float4*>(out_scores + (size_t)t * TOPK + 4) = o;
        float4 e;
        e.x = (float)selE[0]; e.y = (float)selE[1];
        e.z = (float)selE[2]; e.w = (float)selE[3];
        *reinterpret_cast<float4*>(out_sel + (size_t)t * TOPK) = e;
        e.x = (float)selE[4]; e.y = (float)selE[5];
        e.z = (float)selE[6]; e.w = (float)selE[7];
        *reinterpret_cast<float4*>(out_sel + (size_t)t * TOPK + 4) = e;
#pragma unroll
        for (int kk = 0; kk < TOPK; kk++)
          atomicAdd(&out_counts[selE[kk]], 1.0f);
      }
    }
    __syncthreads();  // sc safe to overwrite next iteration
  }
}

extern "C" void kernel_launch(void* const* d_in, const int* in_sizes, int n_in,
                              void* d_out, int out_size, void* d_ws, size_t ws_size,
                              hipStream_t stream) {
  const float* x = (const float*)d_in[0];
  const float* w = (const float*)d_in[1];
  const float* bias = (const float*)d_in[2];
  float* out = (float*)d_out;
  float* out_scores = out;
  float* out_sel = out + T_TOK * TOPK;
  float* out_counts = out + 2 * T_TOK * TOPK;

  char* ws = (char*)d_ws;
  float* scores = (float*)ws;                                   // 16 MB
  _Float16* wh = (_Float16*)(ws + (size_t)16 * 1024 * 1024);    // 1 MB
  _Float16* wlo = (_Float16*)(ws + (size_t)17 * 1024 * 1024);   // 1 MB
  int* wl_count = (int*)(ws + (size_t)18 * 1024 * 1024);
  int* wlist = wl_count + 16;

  prep<<<2048, 256, 0, stream>>>(w, wh, wlo, out_counts, wl_count);
  gate_gemm_mfma<<<512, 256, 0, stream>>>(x, wh, wlo, scores);
  router_serial<<<T_TOK / 64, 64, 0, stream>>>(scores, bias, out_scores,
                                               out_sel, out_counts, wl_count,
                                               wlist);
  fixup_f64<<<2048, 256, 0, stream>>>(x, w, bias, out_scores, out_sel,
                                      out_counts, wl_count, wlist);
}

// Round 9
// 169.430 us; speedup vs baseline: 3.1663x; 1.2362x over previous
//
#include <hip/hip_runtime.h>
#include <math.h>

#define T_TOK 16384
#define DDIM 2048
#define NEXP 256
#define TOPK 8
#define NLIM 4
#define CAPN 6144

constexpr float EPSC = 1e-5f;         // certified score-space error bound
constexpr float SCL = 1.f / 4096.f;   // undo x*16, w*256 scaling

typedef _Float16 half4v __attribute__((ext_vector_type(4)));
typedef _Float16 half8v __attribute__((ext_vector_type(8)));
typedef float f32x4 __attribute__((ext_vector_type(4)));

// ---------------- K0: convert w to fp16 hi/lo + init counts/worklist -------
__global__ __launch_bounds__(256) void prep(
    const float* __restrict__ w, _Float16* __restrict__ wh,
    _Float16* __restrict__ wlo, float* __restrict__ counts,
    int* __restrict__ wl_count) {
  int gid = blockIdx.x * 256 + threadIdx.x;
  float W = w[gid] * 256.f;
  _Float16 h = (_Float16)W;
  wh[gid] = h;
  wlo[gid] = (_Float16)(W - (float)h);
  if (blockIdx.x == 0) {
    counts[threadIdx.x] = 0.f;
    if (threadIdx.x == 0) *wl_count = 0;
  }
}

// --------- K1: MFMA gate GEMM (fp16 split-2) + sigmoid epilogue ------------
constexpr int BM = 64, BN = 128, BK = 64, NT = DDIM / BK;
__global__ __launch_bounds__(256) void gate_gemm_mfma(
    const float* __restrict__ x, const _Float16* __restrict__ wh,
    const _Float16* __restrict__ wlo, float* __restrict__ scores) {
  __shared__ _Float16 Ah[64][72], Al[64][72];
  __shared__ _Float16 Bh[128][72], Bl[128][72];
  const int tid = threadIdx.x;
  const int bid = blockIdx.x;
  const int mb = bid >> 1, nb = bid & 1;
  const int row0 = mb * BM, col0 = nb * BN;
  const int wave = tid >> 6, lane = tid & 63;
  const int m0 = (wave >> 1) * 32, n0 = (wave & 1) * 64;

  f32x4 acc[2][4];
#pragma unroll
  for (int i = 0; i < 2; i++)
#pragma unroll
    for (int j = 0; j < 4; j++) acc[i][j] = (f32x4){0.f, 0.f, 0.f, 0.f};

  float4 ar[4];
  half8v brh[4], brl[4];

  auto LOADT = [&](int t) {
    const int k0 = t * BK;
#pragma unroll
    for (int i = 0; i < 4; i++) {
      int f = i * 256 + tid;
      int r = f >> 4, c4 = (f & 15) << 2;
      ar[i] = *reinterpret_cast<const float4*>(
          x + (size_t)(row0 + r) * DDIM + k0 + c4);
    }
#pragma unroll
    for (int i = 0; i < 4; i++) {
      int f = i * 256 + tid;
      int r = f >> 3, k8 = (f & 7) << 3;
      size_t g = (size_t)(col0 + r) * DDIM + k0 + k8;
      brh[i] = *reinterpret_cast<const half8v*>(wh + g);
      brl[i] = *reinterpret_cast<const half8v*>(wlo + g);
    }
  };
  auto WRITET = [&]() {
#pragma unroll
    for (int i = 0; i < 4; i++) {
      int f = i * 256 + tid;
      int r = f >> 4, c4 = (f & 15) << 2;
      float4 v = ar[i];
      float X0 = v.x * 16.f, X1 = v.y * 16.f, X2 = v.z * 16.f, X3 = v.w * 16.f;
      _Float16 h0 = (_Float16)X0, h1 = (_Float16)X1;
      _Float16 h2 = (_Float16)X2, h3 = (_Float16)X3;
      half4v hv = {h0, h1, h2, h3};
      half4v lv = {(_Float16)(X0 - (float)h0), (_Float16)(X1 - (float)h1),
                   (_Float16)(X2 - (float)h2), (_Float16)(X3 - (float)h3)};
      *reinterpret_cast<half4v*>(&Ah[r][c4]) = hv;
      *reinterpret_cast<half4v*>(&Al[r][c4]) = lv;
    }
#pragma unroll
    for (int i = 0; i < 4; i++) {
      int f = i * 256 + tid;
      int r = f >> 3, k8 = (f & 7) << 3;
      *reinterpret_cast<half8v*>(&Bh[r][k8]) = brh[i];
      *reinterpret_cast<half8v*>(&Bl[r][k8]) = brl[i];
    }
  };

  LOADT(0);
  for (int t = 0; t < NT; t++) {
    WRITET();
    __syncthreads();
    if (t + 1 < NT) LOADT(t + 1);
#pragma unroll
    for (int ks = 0; ks < 2; ks++) {
      const int koff = ks * 32 + (lane >> 4) * 8;
      half8v ah[2], al[2], bh[4], bl[4];
#pragma unroll
      for (int mf = 0; mf < 2; mf++) {
        int r = m0 + mf * 16 + (lane & 15);
        ah[mf] = *reinterpret_cast<half8v*>(&Ah[r][koff]);
        al[mf] = *reinterpret_cast<half8v*>(&Al[r][koff]);
      }
#pragma unroll
      for (int nf = 0; nf < 4; nf++) {
        int c = n0 + nf * 16 + (lane & 15);
        bh[nf] = *reinterpret_cast<half8v*>(&Bh[c][koff]);
        bl[nf] = *reinterpret_cast<half8v*>(&Bl[c][koff]);
      }
#pragma unroll
      for (int mf = 0; mf < 2; mf++)
#pragma unroll
        for (int nf = 0; nf < 4; nf++) {
          acc[mf][nf] = __builtin_amdgcn_mfma_f32_16x16x32_f16(
              ah[mf], bh[nf], acc[mf][nf], 0, 0, 0);
          acc[mf][nf] = __builtin_amdgcn_mfma_f32_16x16x32_f16(
              ah[mf], bl[nf], acc[mf][nf], 0, 0, 0);
          acc[mf][nf] = __builtin_amdgcn_mfma_f32_16x16x32_f16(
              al[mf], bh[nf], acc[mf][nf], 0, 0, 0);
        }
    }
    __syncthreads();
  }
  // epilogue: sigmoid, plain stores
#pragma unroll
  for (int mf = 0; mf < 2; mf++)
#pragma unroll
    for (int nf = 0; nf < 4; nf++)
#pragma unroll
      for (int r = 0; r < 4; r++) {
        int row = row0 + m0 + mf * 16 + (lane >> 4) * 4 + r;
        int col = col0 + n0 + nf * 16 + (lane & 15);
        float sv = 1.f / (1.f + expf(-acc[mf][nf][r] * SCL));
        scores[(size_t)row * NEXP + col] = sv;
      }
}

// -------- K2: serial-lane router: one lane per token, u64-key top-9 --------
__global__ __launch_bounds__(64) void router_serial(
    const float* __restrict__ scores, const float* __restrict__ bias,
    float* __restrict__ out_scores, float* __restrict__ out_sel,
    float* __restrict__ out_counts, int* __restrict__ wl_count,
    int* __restrict__ wlist) {
  __shared__ float S[64][257];  // biased scores; stride 257 -> 2-way banks
  __shared__ float BS[256];
  __shared__ int hist[256];
  const int lane = threadIdx.x;
  const int t0 = blockIdx.x * 64;

#pragma unroll
  for (int i = 0; i < 4; i++) {
    hist[i * 64 + lane] = 0;
    BS[i * 64 + lane] = bias[i * 64 + lane];
  }
  float4 bv = *reinterpret_cast<const float4*>(bias + lane * 4);
  for (int r = 0; r < 64; r++) {
    float4 v = *reinterpret_cast<const float4*>(
        scores + (size_t)(t0 + r) * NEXP + lane * 4);
    S[r][lane * 4 + 0] = v.x + bv.x;
    S[r][lane * 4 + 1] = v.y + bv.y;
    S[r][lane * 4 + 2] = v.z + bv.z;
    S[r][lane * 4 + 3] = v.w + bv.w;
  }
  __syncthreads();

  const float* Srow = S[lane];
  const int t = t0 + lane;

  // phase A: per-group top-2 sums
  float gsArr[8];
#pragma unroll
  for (int g = 0; g < 8; g++) {
    float m1 = -INFINITY, m2 = -INFINITY;
#pragma unroll 4
    for (int k = 0; k < 32; k++) {
      float c = Srow[g * 32 + k];
      float mx = fmaxf(m1, c);
      m2 = fmaxf(m2, fminf(m1, c));
      m1 = mx;
    }
    gsArr[g] = m1 + m2;
  }

  // group ranks -> kept nibble-pack, 4th/5th margin
  int kgpack = 0;
  float v4 = 0.f, v5 = 0.f;
#pragma unroll
  for (int g = 7; g >= 0; g--) {
    int rk = 0;
#pragma unroll
    for (int h = 0; h < 8; h++)
      rk += (gsArr[h] > gsArr[g]) || (gsArr[h] == gsArr[g] && h < g);
    if (rk < NLIM) kgpack = (kgpack << 4) | g;
    if (rk == 3) v4 = gsArr[g];
    if (rk == 4) v5 = gsArr[g];
  }
  bool flag = (v4 - v5) < 8.f * EPSC;

  // phase B: branchless 9-slot insertion over 128 eligible, u64 keys
  unsigned long long L[9];
#pragma unroll
  for (int i = 0; i < 9; i++) L[i] = 0ULL;
#pragma unroll
  for (int gi = 0; gi < 4; gi++) {
    const int cb = ((kgpack >> (gi * 4)) & 15) * 32;
#pragma unroll 2
    for (int k = 0; k < 32; k++) {
      float c = Srow[cb + k];
      unsigned int bits = __float_as_uint(c + 1.0f);
      unsigned long long key =
          ((unsigned long long)bits << 8) | (unsigned)(255 - (cb + k));
#pragma unroll
      for (int sl = 0; sl < 9; sl++) {
        bool gt = key > L[sl];
        unsigned long long nl = gt ? key : L[sl];
        key = gt ? L[sl] : key;
        L[sl] = nl;
      }
    }
  }

  int selE[9];
  float cval[9];
#pragma unroll
  for (int i = 0; i < 9; i++) {
    selE[i] = 255 - (int)(L[i] & 0xFFULL);
    cval[i] = __uint_as_float((unsigned)(L[i] >> 8)) - 1.0f;
  }
#pragma unroll
  for (int i = 0; i < 8; i++)
    flag = flag || ((cval[i] - cval[i + 1]) < 2.f * EPSC);

  if (!flag) {
    float s[8];
    float denom = 1e-20f;
#pragma unroll
    for (int i = 0; i < 8; i++) {
      s[i] = Srow[selE[i]] - BS[selE[i]];
      denom += s[i];
    }
    float scale = 2.5f / denom;
    float4 o0 = {s[0] * scale, s[1] * scale, s[2] * scale, s[3] * scale};
    float4 o1 = {s[4] * scale, s[5] * scale, s[6] * scale, s[7] * scale};
    *reinterpret_cast<float4*>(out_scores + (size_t)t * TOPK) = o0;
    *reinterpret_cast<float4*>(out_scores + (size_t)t * TOPK + 4) = o1;
    float4 e0 = {(float)selE[0], (float)selE[1], (float)selE[2], (float)selE[3]};
    float4 e1 = {(float)selE[4], (float)selE[5], (float)selE[6], (float)selE[7]};
    *reinterpret_cast<float4*>(out_sel + (size_t)t * TOPK) = e0;
    *reinterpret_cast<float4*>(out_sel + (size_t)t * TOPK + 4) = e1;
#pragma unroll
    for (int i = 0; i < 8; i++) atomicAdd(&hist[selE[i]], 1);
  } else {
    int i = atomicAdd(wl_count, 1);
    wlist[i] = t;
  }
  __syncthreads();
#pragma unroll
  for (int i = 0; i < 4; i++) {
    int h = hist[i * 64 + lane];
    if (h) atomicAdd(&out_counts[i * 64 + lane], (float)h);
  }
}

// ---- K3a: f64 logits for flagged tokens; block = (token-quad, 16 experts) -
__global__ __launch_bounds__(256) void fixup_logits(
    const float* __restrict__ x, const float* __restrict__ w,
    const int* __restrict__ wl_count, const int* __restrict__ wlist,
    double* __restrict__ scG) {
  __shared__ float xs[4][DDIM];  // 32 KB
  __shared__ int toks[4];
  const int n = min(*wl_count, CAPN);
  const int nq = (n + 3) >> 2;
  const int nwork = nq * 16;
  const int tid = threadIdx.x;
  const int wv = tid >> 6, lane = tid & 63;

  for (int wk = blockIdx.x; wk < nwork; wk += gridDim.x) {
    const int q = wk >> 4, ec = wk & 15;
    __syncthreads();
    if (tid < 4) {
      int idx = q * 4 + tid;
      toks[tid] = wlist[idx < n ? idx : (n - 1)];
    }
    __syncthreads();
    for (int i = tid; i < 4 * 512; i += 256) {
      int tk = i >> 9, off = i & 511;
      reinterpret_cast<float4*>(xs[tk])[off] =
          reinterpret_cast<const float4*>(x + (size_t)toks[tk] * DDIM)[off];
    }
    __syncthreads();

#pragma unroll 1
    for (int ei = 0; ei < 4; ei++) {
      const int e = ec * 16 + wv * 4 + ei;
      const float* wr = w + (size_t)e * DDIM + lane * 4;
      float4 wreg[8];
#pragma unroll
      for (int j = 0; j < 8; j++)
        wreg[j] = *reinterpret_cast<const float4*>(wr + j * 256);
      double p0 = 0, p1 = 0, p2 = 0, p3 = 0;
#pragma unroll
      for (int j = 0; j < 8; j++) {
        const int k = j * 256 + lane * 4;
        float4 wv4 = wreg[j];
        float4 x0 = *reinterpret_cast<const float4*>(&xs[0][k]);
        float4 x1 = *reinterpret_cast<const float4*>(&xs[1][k]);
        float4 x2 = *reinterpret_cast<const float4*>(&xs[2][k]);
        float4 x3 = *reinterpret_cast<const float4*>(&xs[3][k]);
        p0 = fma((double)x0.x, (double)wv4.x, p0);
        p0 = fma((double)x0.y, (double)wv4.y, p0);
        p0 = fma((double)x0.z, (double)wv4.z, p0);
        p0 = fma((double)x0.w, (double)wv4.w, p0);
        p1 = fma((double)x1.x, (double)wv4.x, p1);
        p1 = fma((double)x1.y, (double)wv4.y, p1);
        p1 = fma((double)x1.z, (double)wv4.z, p1);
        p1 = fma((double)x1.w, (double)wv4.w, p1);
        p2 = fma((double)x2.x, (double)wv4.x, p2);
        p2 = fma((double)x2.y, (double)wv4.y, p2);
        p2 = fma((double)x2.z, (double)wv4.z, p2);
        p2 = fma((double)x2.w, (double)wv4.w, p2);
        p3 = fma((double)x3.x, (double)wv4.x, p3);
        p3 = fma((double)x3.y, (double)wv4.y, p3);
        p3 = fma((double)x3.z, (double)wv4.z, p3);
        p3 = fma((double)x3.w, (double)wv4.w, p3);
      }
#pragma unroll
      for (int d = 1; d <= 32; d <<= 1) {
        p0 += __shfl_xor(p0, d);
        p1 += __shfl_xor(p1, d);
        p2 += __shfl_xor(p2, d);
        p3 += __shfl_xor(p3, d);
      }
      if (lane == 0) {
        const int it0 = q * 4;
        if (it0 + 0 < n) scG[(size_t)(it0 + 0) * NEXP + e] = 1.0 / (1.0 + exp(-p0));
        if (it0 + 1 < n) scG[(size_t)(it0 + 1) * NEXP + e] = 1.0 / (1.0 + exp(-p1));
        if (it0 + 2 < n) scG[(size_t)(it0 + 2) * NEXP + e] = 1.0 / (1.0 + exp(-p2));
        if (it0 + 3 < n) scG[(size_t)(it0 + 3) * NEXP + e] = 1.0 / (1.0 + exp(-p3));
      }
    }
  }
}

// ---- K3b: exact f64 selection per flagged token (reads scG) ---------------
__global__ __launch_bounds__(256) void fixup_select(
    const double* __restrict__ scG, const float* __restrict__ x,
    const float* __restrict__ w, const float* __restrict__ bias,
    float* __restrict__ out_scores, float* __restrict__ out_sel,
    float* __restrict__ out_counts, const int* __restrict__ wl_count,
    const int* __restrict__ wlist) {
  __shared__ double sc[NEXP];
  const int n = *wl_count;
  const int tid = threadIdx.x;
  const int wv = tid >> 6, lane = tid & 63;

  for (int it = blockIdx.x; it < n; it += gridDim.x) {
    const int t = wlist[it];
    __syncthreads();
    if (it < CAPN) {
      sc[tid] = scG[(size_t)it * NEXP + tid];
    } else {
      // fallback (never taken at observed n): compute inline, round-8 style
      const float* xrow = x + (size_t)t * DDIM + lane * 8;
      float4 xr[4][2];
#pragma unroll
      for (int p = 0; p < 4; p++) {
        xr[p][0] = *reinterpret_cast<const float4*>(xrow + p * 512);
        xr[p][1] = *reinterpret_cast<const float4*>(xrow + p * 512 + 4);
      }
      double myLogit = 0.0;
      for (int e = 0; e < 64; e++) {
        const float* wr = w + (size_t)(wv * 64 + e) * DDIM + lane * 8;
        double a0 = 0, a1 = 0;
#pragma unroll
        for (int p = 0; p < 4; p++) {
          float4 w0 = *reinterpret_cast<const float4*>(wr + p * 512);
          float4 w1 = *reinterpret_cast<const float4*>(wr + p * 512 + 4);
          a0 = fma((double)xr[p][0].x, (double)w0.x, a0);
          a1 = fma((double)xr[p][0].y, (double)w0.y, a1);
          a0 = fma((double)xr[p][0].z, (double)w0.z, a0);
          a1 = fma((double)xr[p][0].w, (double)w0.w, a1);
          a0 = fma((double)xr[p][1].x, (double)w1.x, a0);
          a1 = fma((double)xr[p][1].y, (double)w1.y, a1);
          a0 = fma((double)xr[p][1].z, (double)w1.z, a0);
          a1 = fma((double)xr[p][1].w, (double)w1.w, a1);
        }
        double tot = a0 + a1;
#pragma unroll
        for (int d = 1; d <= 32; d <<= 1) tot += __shfl_xor(tot, d);
        if (lane == e) myLogit = tot;
      }
      sc[wv * 64 + lane] = 1.0 / (1.0 + exp(-myLogit));
    }
    __syncthreads();

    if (tid < 64) {
      double s[4], c[4];
      s[0] = sc[lane * 4 + 0]; s[1] = sc[lane * 4 + 1];
      s[2] = sc[lane * 4 + 2]; s[3] = sc[lane * 4 + 3];
      float4 bvv = *reinterpret_cast<const float4*>(bias + lane * 4);
      c[0] = s[0] + (double)bvv.x; c[1] = s[1] + (double)bvv.y;
      c[2] = s[2] + (double)bvv.z; c[3] = s[3] + (double)bvv.w;

      double h1 = fmax(c[0], c[1]), l1 = fmin(c[0], c[1]);
      double h2 = fmax(c[2], c[3]), l2 = fmin(c[2], c[3]);
      double m1 = fmax(h1, h2);
      double m2 = fmax(fmin(h1, h2), fmax(l1, l2));
#pragma unroll
      for (int d = 1; d <= 4; d <<= 1) {
        double om1 = __shfl_xor(m1, d);
        double om2 = __shfl_xor(m2, d);
        double n1 = fmax(m1, om1);
        double n2 = fmax(fmin(m1, om1), fmax(m2, om2));
        m1 = n1; m2 = n2;
      }
      double gscore = m1 + m2;
      double gsv[8];
#pragma unroll
      for (int g = 0; g < 8; g++) gsv[g] = __shfl(gscore, g * 8);
      const int gme = lane >> 3;
      int rank = 0;
#pragma unroll
      for (int h = 0; h < 8; h++)
        rank += (gsv[h] > gsv[gme]) || (gsv[h] == gsv[gme] && h < gme);
      const bool keep = rank < NLIM;

      const double NEG = -HUGE_VAL;
      double v[4];
#pragma unroll
      for (int j = 0; j < 4; j++) v[j] = keep ? c[j] : NEG;

      double selS[TOPK];
      int selE[TOPK];
#pragma unroll
      for (int kk = 0; kk < TOPK; kk++) {
        double bvv2 = v[0];
        int bi = lane * 4;
#pragma unroll
        for (int j = 1; j < 4; j++)
          if (v[j] > bvv2) { bvv2 = v[j]; bi = lane * 4 + j; }
#pragma unroll
        for (int d = 1; d <= 32; d <<= 1) {
          double ov = __shfl_xor(bvv2, d);
          int oi = __shfl_xor(bi, d);
          if (ov > bvv2 || (ov == bvv2 && oi < bi)) { bvv2 = ov; bi = oi; }
        }
        selE[kk] = bi;
        int ol = bi >> 2, oj = bi & 3;
        double cand = (oj == 0) ? s[0] : (oj == 1) ? s[1] : (oj == 2) ? s[2] : s[3];
        selS[kk] = __shfl(cand, ol);
#pragma unroll
        for (int j = 0; j < 4; j++)
          if (lane == ol && j == oj) v[j] = NEG;
      }

      double denom = 1e-20;
#pragma unroll
      for (int kk = 0; kk < TOPK; kk++) denom += selS[kk];
      double scale = 2.5 / denom;

      if (lane == 0) {
        float4 o;
        o.x = (float)(selS[0] * scale); o.y = (float)(selS[1] * scale);
        o.z = (float)(selS[2] * scale); o.w = (float)(selS[3] * scale);
        *reinterpret_cast<float4*>(out_scores + (size_t)t * TOPK) = o;
        o.x = (float)(selS[4] * scale); o.y = (float)(selS[5] * scale);
        o.z = (float)(selS[6] * scale); o.w = (float)(selS[7] * scale);
        *reinterpret_cast<float4*>(out_scores + (size_t)t * TOPK + 4) = o;
        float4 e;
        e.x = (float)selE[0]; e.y = (float)selE[1];
        e.z = (float)selE[2]; e.w = (float)selE[3];
        *reinterpret_cast<float4*>(out_sel + (size_t)t * TOPK) = e;
        e.x = (float)selE[4]; e.y = (float)selE[5];
        e.z = (float)selE[6]; e.w = (float)selE[7];
        *reinterpret_cast<float4*>(out_sel + (size_t)t * TOPK + 4) = e;
#pragma unroll
        for (int kk = 0; kk < TOPK; kk++)
          atomicAdd(&out_counts[selE[kk]], 1.0f);
      }
    }
    __syncthreads();
  }
}

extern "C" void kernel_launch(void* const* d_in, const int* in_sizes, int n_in,
                              void* d_out, int out_size, void* d_ws, size_t ws_size,
                              hipStream_t stream) {
  const float* x = (const float*)d_in[0];
  const float* w = (const float*)d_in[1];
  const float* bias = (const float*)d_in[2];
  float* out = (float*)d_out;
  float* out_scores = out;
  float* out_sel = out + T_TOK * TOPK;
  float* out_counts = out + 2 * T_TOK * TOPK;

  char* ws = (char*)d_ws;
  float* scores = (float*)ws;                                   // 16 MiB
  _Float16* wh = (_Float16*)(ws + (size_t)16 * 1024 * 1024);    // 1 MiB
  _Float16* wlo = (_Float16*)(ws + (size_t)17 * 1024 * 1024);   // 1 MiB
  int* wl_count = (int*)(ws + (size_t)18 * 1024 * 1024);
  int* wlist = wl_count + 16;
  double* scG = (double*)(ws + (size_t)19 * 1024 * 1024);       // <= 12.6 MiB

  prep<<<2048, 256, 0, stream>>>(w, wh, wlo, out_counts, wl_count);
  gate_gemm_mfma<<<512, 256, 0, stream>>>(x, wh, wlo, scores);
  router_serial<<<T_TOK / 64, 64, 0, stream>>>(scores, bias, out_scores,
                                               out_sel, out_counts, wl_count,
                                               wlist);
  fixup_logits<<<4096, 256, 0, stream>>>(x, w, wl_count, wlist, scG);
  fixup_select<<<2048, 256, 0, stream>>>(scG, x, w, bias, out_scores, out_sel,
                                         out_counts, wl_count, wlist);
}